// Round 4
// baseline (985.752 us; speedup 1.0000x reference)
//
#include <hip/hip_runtime.h>

#define NN 100000
#define NE 1600000
#define BSH 7                 // log2(nodes per bucket)
#define BSZ 128               // nodes per bucket
#define NBKT 782              // ceil(NN/BSZ)
#define NPB 256               // partition blocks
#define EPB 6250              // edges per partition block (NE/NPB, exact)

// ---------------- zero bucket counters ----------------
__global__ __launch_bounds__(256) void k_zero(int* __restrict__ bktcnt) {
    int i = blockIdx.x * 256 + threadIdx.x;
    if (i < NBKT) bktcnt[i] = 0;
}

// ---------------- bucket histogram (LDS-privatized) ----------------
__global__ __launch_bounds__(256) void k_hist(const int* __restrict__ dst,
                                              int* __restrict__ bktcnt) {
    __shared__ int cnt[NBKT];
    int tid = threadIdx.x;
    for (int i = tid; i < NBKT; i += 256) cnt[i] = 0;
    __syncthreads();
    int e0 = blockIdx.x * EPB;
    for (int j = tid; j < EPB; j += 256)
        atomicAdd(&cnt[dst[e0 + j] >> BSH], 1);
    __syncthreads();
    for (int i = tid; i < NBKT; i += 256)
        if (cnt[i]) atomicAdd(&bktcnt[i], cnt[i]);
}

// ---------------- scan 782 bucket counts ----------------
__global__ __launch_bounds__(1024) void k_scan(const int* __restrict__ bktcnt,
                                               int* __restrict__ bktbase,
                                               int* __restrict__ cursor) {
    __shared__ int s[1024];
    int t = threadIdx.x;
    s[t] = (t < NBKT) ? bktcnt[t] : 0;
    __syncthreads();
    #pragma unroll
    for (int off = 1; off < 1024; off <<= 1) {
        int add = (t >= off) ? s[t - off] : 0;
        __syncthreads();
        s[t] += add;
        __syncthreads();
    }
    if (t < NBKT) {
        int b = (t == 0) ? 0 : s[t - 1];
        bktbase[t] = b;
        cursor[t]  = b;
    }
    if (t == 0) bktbase[NBKT] = NE;
}

// ---------------- partition edges into buckets: rec = (w_bits, src<<7|dstLo) ----------------
__global__ __launch_bounds__(256) void k_part(const int* __restrict__ src,
                                              const int* __restrict__ dst,
                                              const float* __restrict__ w,
                                              int* __restrict__ cursor,
                                              uint2* __restrict__ rec) {
    __shared__ int cnt[NBKT];
    __shared__ int base[NBKT];
    int tid = threadIdx.x;
    for (int i = tid; i < NBKT; i += 256) cnt[i] = 0;
    __syncthreads();
    int e0 = blockIdx.x * EPB;
    for (int j = tid; j < EPB; j += 256)
        atomicAdd(&cnt[dst[e0 + j] >> BSH], 1);
    __syncthreads();
    for (int i = tid; i < NBKT; i += 256) {
        int c = cnt[i];
        base[i] = c ? atomicAdd(&cursor[i], c) : 0;  // one global atomic per (block,bucket)
    }
    __syncthreads();
    for (int i = tid; i < NBKT; i += 256) cnt[i] = 0;
    __syncthreads();
    for (int j = tid; j < EPB; j += 256) {
        int e  = e0 + j;
        int d  = dst[e];
        int bk = d >> BSH;
        int slot = base[bk] + atomicAdd(&cnt[bk], 1);   // LDS cursor
        rec[slot] = make_uint2(__float_as_uint(w[e]),
                               ((unsigned)src[e] << BSH) | (unsigned)(d & (BSZ - 1)));
    }
}

// ---------------- per-bucket weighted degree -> dis (LDS atomics only) ----------------
__global__ __launch_bounds__(256) void k_deg(const int* __restrict__ bktbase,
                                             const uint2* __restrict__ rec,
                                             float* __restrict__ dis) {
    __shared__ float dw[BSZ];
    int b = blockIdx.x, tid = threadIdx.x;
    if (tid < BSZ) dw[tid] = 1.0f;   // self-loop weight
    __syncthreads();
    int s = bktbase[b], e = bktbase[b + 1];
    for (int j = s + tid; j < e; j += 256) {
        uint2 r = rec[j];
        atomicAdd(&dw[r.y & (BSZ - 1)], __uint_as_float(r.x));
    }
    __syncthreads();
    if (tid < BSZ) {
        int node = b * BSZ + tid;
        if (node < NN) dis[node] = rsqrtf(dw[tid]);
    }
}

// ---------------- h1 = x @ W1  (x:[NN,128], W1:[128,64]), 80-row tiles ----------------
#define XPAD 136
#define FMA4(a, s, b) { a.x = fmaf(s, b.x, a.x); a.y = fmaf(s, b.y, a.y); \
                        a.z = fmaf(s, b.z, a.z); a.w = fmaf(s, b.w, a.w); }

__global__ __launch_bounds__(320) void k_gemm1(const float* __restrict__ x,
                                               const float* __restrict__ W,
                                               float* __restrict__ h) {
    __shared__ float xs[80 * XPAD];
    __shared__ float Ws[128 * 64];
    int tid  = threadIdx.x;
    int row0 = blockIdx.x * 80;

    for (int j = tid; j < 2048; j += 320)
        ((float4*)Ws)[j] = ((const float4*)W)[j];
    for (int j = tid; j < 2560; j += 320) {
        int r = j >> 5, kq = j & 31;
        *(float4*)&xs[r * XPAD + kq * 4] =
            *(const float4*)&x[(row0 + r) * 128 + kq * 4];
    }
    __syncthreads();

    int cg = tid & 15, rg = tid >> 4;
    int c0 = cg * 4, r0 = rg * 4;

    float4 acc0 = {0,0,0,0}, acc1 = {0,0,0,0}, acc2 = {0,0,0,0}, acc3 = {0,0,0,0};
    #pragma unroll
    for (int kq = 0; kq < 32; ++kq) {
        float4 xv0 = *(const float4*)&xs[(r0 + 0) * XPAD + kq * 4];
        float4 xv1 = *(const float4*)&xs[(r0 + 1) * XPAD + kq * 4];
        float4 xv2 = *(const float4*)&xs[(r0 + 2) * XPAD + kq * 4];
        float4 xv3 = *(const float4*)&xs[(r0 + 3) * XPAD + kq * 4];
        float4 wv0 = *(const float4*)&Ws[(kq * 4 + 0) * 64 + c0];
        float4 wv1 = *(const float4*)&Ws[(kq * 4 + 1) * 64 + c0];
        float4 wv2 = *(const float4*)&Ws[(kq * 4 + 2) * 64 + c0];
        float4 wv3 = *(const float4*)&Ws[(kq * 4 + 3) * 64 + c0];
        FMA4(acc0, xv0.x, wv0); FMA4(acc0, xv0.y, wv1); FMA4(acc0, xv0.z, wv2); FMA4(acc0, xv0.w, wv3);
        FMA4(acc1, xv1.x, wv0); FMA4(acc1, xv1.y, wv1); FMA4(acc1, xv1.z, wv2); FMA4(acc1, xv1.w, wv3);
        FMA4(acc2, xv2.x, wv0); FMA4(acc2, xv2.y, wv1); FMA4(acc2, xv2.z, wv2); FMA4(acc2, xv2.w, wv3);
        FMA4(acc3, xv3.x, wv0); FMA4(acc3, xv3.y, wv1); FMA4(acc3, xv3.z, wv2); FMA4(acc3, xv3.w, wv3);
    }

    float* hp = h + (row0 + r0) * 64 + c0;
    *(float4*)(hp)       = acc0;
    *(float4*)(hp + 64)  = acc1;
    *(float4*)(hp + 128) = acc2;
    *(float4*)(hp + 192) = acc3;
}

// ---------------- layer-1 aggregation: bucket tile in LDS, wave = edge, lane = feature ----------------
__global__ __launch_bounds__(512) void k_agg1(const int* __restrict__ bktbase,
                                              const uint2* __restrict__ rec,
                                              const float* __restrict__ h1,
                                              const float* __restrict__ dis,
                                              const float* __restrict__ b1,
                                              float* __restrict__ xemb) {
    __shared__ float tile[BSZ * 64];   // 32 KB
    __shared__ float disl[BSZ];
    int b = blockIdx.x, tid = threadIdx.x;
    int node0 = b * BSZ;
    if (tid < BSZ) {
        int node = node0 + tid;
        disl[tid] = (node < NN) ? dis[node] : 0.f;
    }
    __syncthreads();
    // init: bias + self-loop message
    for (int i = tid; i < BSZ * 64; i += 512) {
        int n = i >> 6, f = i & 63;
        int node = node0 + n;
        float d = disl[n];
        tile[i] = (node < NN) ? fmaf(d * d, h1[node * 64 + f], b1[f]) : 0.f;
    }
    __syncthreads();

    int s = bktbase[b], e = bktbase[b + 1];
    int wave = tid >> 6, f = tid & 63;
    int j = s + wave;
    if (j < e) {
        uint2 r = rec[j];                       // software pipeline: 1-ahead
        int   srcn = (int)(r.y >> BSH);
        float dsrc = dis[srcn];
        float v    = h1[srcn * 64 + f];
        for (; j + 8 < e; j += 8) {
            uint2 rn    = rec[j + 8];
            int   srcn2 = (int)(rn.y >> BSH);
            float dsrc2 = dis[srcn2];
            float v2    = h1[srcn2 * 64 + f];
            int   dl    = r.y & (BSZ - 1);
            float nrm   = dsrc * __uint_as_float(r.x) * disl[dl];
            atomicAdd(&tile[dl * 64 + f], nrm * v);
            r = rn; srcn = srcn2; dsrc = dsrc2; v = v2;
        }
        int   dl  = r.y & (BSZ - 1);
        float nrm = dsrc * __uint_as_float(r.x) * disl[dl];
        atomicAdd(&tile[dl * 64 + f], nrm * v);
    }
    __syncthreads();
    for (int i = tid; i < BSZ * 64; i += 512) {
        int idx = node0 * 64 + i;
        if (idx < NN * 64) xemb[idx] = tile[i];
    }
}

// ---------------- h3 = relu(x_emb) @ W2   (W2:[64,16]) ----------------
__global__ __launch_bounds__(256) void k_gemm2(const float* __restrict__ xemb,
                                               const float* __restrict__ W,
                                               float* __restrict__ h3) {
    __shared__ float Ws[64 * 16];
    __shared__ float xs[16][65];
    int tid  = threadIdx.x;
    int row0 = blockIdx.x * 16;

    for (int i = tid; i < 64 * 16; i += 256) Ws[i] = W[i];
    for (int i = tid; i < 16 * 64; i += 256) {
        float v = xemb[row0 * 64 + i];
        xs[i >> 6][i & 63] = v > 0.0f ? v : 0.0f;  // fused ReLU
    }
    __syncthreads();

    int col = tid & 15, r = tid >> 4;
    float a = 0.f;
    #pragma unroll
    for (int k = 0; k < 64; ++k) a = fmaf(xs[r][k], Ws[k * 16 + col], a);
    h3[(row0 + r) * 16 + col] = a;
}

// ---------------- layer-2 aggregation: 16 lanes/edge, 4 edges/wave ----------------
__global__ __launch_bounds__(512) void k_agg2(const int* __restrict__ bktbase,
                                              const uint2* __restrict__ rec,
                                              const float* __restrict__ h3,
                                              const float* __restrict__ dis,
                                              const float* __restrict__ b2,
                                              float* __restrict__ out) {
    __shared__ float tile[BSZ * 16];   // 8 KB
    __shared__ float disl[BSZ];
    int b = blockIdx.x, tid = threadIdx.x;
    int node0 = b * BSZ;
    if (tid < BSZ) {
        int node = node0 + tid;
        disl[tid] = (node < NN) ? dis[node] : 0.f;
    }
    __syncthreads();
    for (int i = tid; i < BSZ * 16; i += 512) {
        int n = i >> 4, f = i & 15;
        int node = node0 + n;
        float d = disl[n];
        tile[i] = (node < NN) ? fmaf(d * d, h3[node * 16 + f], b2[f]) : 0.f;
    }
    __syncthreads();

    int s = bktbase[b], e = bktbase[b + 1];
    int lane16 = tid & 15;
    int grp    = tid >> 4;         // 32 groups of 16 lanes across the block
    int j = s + grp;
    if (j < e) {
        uint2 r = rec[j];
        int   srcn = (int)(r.y >> BSH);
        float dsrc = dis[srcn];
        float v    = h3[srcn * 16 + lane16];
        for (; j + 32 < e; j += 32) {
            uint2 rn    = rec[j + 32];
            int   srcn2 = (int)(rn.y >> BSH);
            float dsrc2 = dis[srcn2];
            float v2    = h3[srcn2 * 16 + lane16];
            int   dl    = r.y & (BSZ - 1);
            float nrm   = dsrc * __uint_as_float(r.x) * disl[dl];
            atomicAdd(&tile[dl * 16 + lane16], nrm * v);
            r = rn; srcn = srcn2; dsrc = dsrc2; v = v2;
        }
        int   dl  = r.y & (BSZ - 1);
        float nrm = dsrc * __uint_as_float(r.x) * disl[dl];
        atomicAdd(&tile[dl * 16 + lane16], nrm * v);
    }
    __syncthreads();
    for (int i = tid; i < BSZ * 16; i += 512) {
        int idx = node0 * 16 + i;
        if (idx < NN * 16) out[idx] = tile[i];
    }
}

extern "C" void kernel_launch(void* const* d_in, const int* in_sizes, int n_in,
                              void* d_out, int out_size, void* d_ws, size_t ws_size,
                              hipStream_t stream) {
    const float* x  = (const float*)d_in[0];
    const int*   ei = (const int*)d_in[1];
    const float* w  = (const float*)d_in[2];
    const float* W1 = (const float*)d_in[3];
    const float* b1 = (const float*)d_in[4];
    const float* W2 = (const float*)d_in[5];
    const float* b2 = (const float*)d_in[6];
    const int* src = ei;
    const int* dst = ei + NE;

    float* out2 = (float*)d_out;               // [NN,16]  output 0
    float* xemb = (float*)d_out + NN * 16;     // [NN,64]  output 1

    // workspace: rec 12.8MB | h1 25.6MB | h3 6.4MB | dis 0.4MB | counters
    uint2* rec     = (uint2*)d_ws;
    float* h1      = (float*)(rec + NE);
    float* h3      = h1 + (size_t)NN * 64;
    float* dis     = h3 + (size_t)NN * 16;
    int*   bktcnt  = (int*)(dis + NN);
    int*   bktbase = bktcnt + NBKT;
    int*   cursor  = bktbase + NBKT + 1;

    k_zero <<<(NBKT + 255) / 256, 256, 0, stream>>>(bktcnt);
    k_hist <<<NPB,  256, 0, stream>>>(dst, bktcnt);
    k_scan <<<1,   1024, 0, stream>>>(bktcnt, bktbase, cursor);
    k_part <<<NPB,  256, 0, stream>>>(src, dst, w, cursor, rec);
    k_deg  <<<NBKT, 256, 0, stream>>>(bktbase, rec, dis);

    k_gemm1<<<NN / 80, 320, 0, stream>>>(x, W1, h1);
    k_agg1 <<<NBKT, 512, 0, stream>>>(bktbase, rec, h1, dis, b1, xemb);

    k_gemm2<<<NN / 16, 256, 0, stream>>>(xemb, W2, h3);
    k_agg2 <<<NBKT, 512, 0, stream>>>(bktbase, rec, h3, dis, b2, out2);
}

// Round 5
// 295.911 us; speedup vs baseline: 3.3312x; 3.3312x over previous
//
#include <hip/hip_runtime.h>

#define NN 100000
#define NE 1600000
#define BSH 7                 // log2(nodes per bucket)
#define BSZ 128               // nodes per bucket
#define NBKT 782              // ceil(NN/BSZ)
#define NPB 256               // partition blocks
#define EPB 6250              // edges per partition block (NE/NPB, exact)

// ---------------- zero bucket counters ----------------
__global__ __launch_bounds__(256) void k_zero(int* __restrict__ bktcnt) {
    int i = blockIdx.x * 256 + threadIdx.x;
    if (i < NBKT) bktcnt[i] = 0;
}

// ---------------- bucket histogram (LDS-privatized) ----------------
__global__ __launch_bounds__(256) void k_hist(const int* __restrict__ dst,
                                              int* __restrict__ bktcnt) {
    __shared__ int cnt[NBKT];
    int tid = threadIdx.x;
    for (int i = tid; i < NBKT; i += 256) cnt[i] = 0;
    __syncthreads();
    int e0 = blockIdx.x * EPB;
    for (int j = tid; j < EPB; j += 256)
        atomicAdd(&cnt[dst[e0 + j] >> BSH], 1);
    __syncthreads();
    for (int i = tid; i < NBKT; i += 256)
        if (cnt[i]) atomicAdd(&bktcnt[i], cnt[i]);
}

// ---------------- scan 782 bucket counts ----------------
__global__ __launch_bounds__(1024) void k_scan(const int* __restrict__ bktcnt,
                                               int* __restrict__ bktbase,
                                               int* __restrict__ cursor,
                                               int* __restrict__ row_ptr) {
    __shared__ int s[1024];
    int t = threadIdx.x;
    s[t] = (t < NBKT) ? bktcnt[t] : 0;
    __syncthreads();
    #pragma unroll
    for (int off = 1; off < 1024; off <<= 1) {
        int add = (t >= off) ? s[t - off] : 0;
        __syncthreads();
        s[t] += add;
        __syncthreads();
    }
    if (t < NBKT) {
        int b = (t == 0) ? 0 : s[t - 1];
        bktbase[t] = b;
        cursor[t]  = b;
    }
    if (t == 0) { bktbase[NBKT] = NE; row_ptr[NN] = NE; }
}

// ---------------- partition edges into buckets: rec = (w_bits, src<<7|dstLo) ----------------
__global__ __launch_bounds__(256) void k_part(const int* __restrict__ src,
                                              const int* __restrict__ dst,
                                              const float* __restrict__ w,
                                              int* __restrict__ cursor,
                                              uint2* __restrict__ rec) {
    __shared__ int cnt[NBKT];
    __shared__ int base[NBKT];
    int tid = threadIdx.x;
    for (int i = tid; i < NBKT; i += 256) cnt[i] = 0;
    __syncthreads();
    int e0 = blockIdx.x * EPB;
    for (int j = tid; j < EPB; j += 256)
        atomicAdd(&cnt[dst[e0 + j] >> BSH], 1);
    __syncthreads();
    for (int i = tid; i < NBKT; i += 256) {
        int c = cnt[i];
        base[i] = c ? atomicAdd(&cursor[i], c) : 0;  // one global atomic per (block,bucket)
    }
    __syncthreads();
    for (int i = tid; i < NBKT; i += 256) cnt[i] = 0;
    __syncthreads();
    for (int j = tid; j < EPB; j += 256) {
        int e  = e0 + j;
        int d  = dst[e];
        int bk = d >> BSH;
        int slot = base[bk] + atomicAdd(&cnt[bk], 1);   // LDS cursor
        rec[slot] = make_uint2(__float_as_uint(w[e]),
                               ((unsigned)src[e] << BSH) | (unsigned)(d & (BSZ - 1)));
    }
}

// ---------------- per-bucket: deg -> dis, counting-sort to per-node CSR ----------------
// rec2[pos] = (w * dis[dst], src) sorted by dst; row_ptr[node] = start
__global__ __launch_bounds__(256) void k_build(const int* __restrict__ bktbase,
                                               const uint2* __restrict__ rec,
                                               uint2* __restrict__ rec2,
                                               float* __restrict__ dis,
                                               int* __restrict__ row_ptr) {
    __shared__ float dw[BSZ];
    __shared__ int   cnt[BSZ];
    __shared__ int   base[BSZ];
    __shared__ int   scn[BSZ];
    __shared__ float disl[BSZ];
    int b = blockIdx.x, tid = threadIdx.x;
    int s = bktbase[b], e = bktbase[b + 1];
    if (tid < BSZ) { dw[tid] = 1.0f; cnt[tid] = 0; }   // self-loop weight
    __syncthreads();
    for (int j = s + tid; j < e; j += 256) {
        uint2 r = rec[j];
        int dl = r.y & (BSZ - 1);
        atomicAdd(&cnt[dl], 1);
        atomicAdd(&dw[dl], __uint_as_float(r.x));
    }
    __syncthreads();
    if (tid < BSZ) scn[tid] = cnt[tid];
    __syncthreads();
    #pragma unroll
    for (int off = 1; off < BSZ; off <<= 1) {          // Hillis-Steele over 128
        int add = (tid < BSZ && tid >= off) ? scn[tid - off] : 0;
        __syncthreads();
        if (tid < BSZ) scn[tid] += add;
        __syncthreads();
    }
    if (tid < BSZ) {
        int node = b * BSZ + tid;
        base[tid] = (tid == 0) ? 0 : scn[tid - 1];
        float d = rsqrtf(dw[tid]);                     // dw >= 1 always
        disl[tid] = d;
        if (node < NN) { dis[node] = d; row_ptr[node] = s + base[tid]; }
        cnt[tid] = 0;                                   // reuse as cursor
    }
    __syncthreads();
    for (int j = s + tid; j < e; j += 256) {
        uint2 r = rec[j];
        int dl = r.y & (BSZ - 1);
        int pos = s + base[dl] + atomicAdd(&cnt[dl], 1);
        rec2[pos] = make_uint2(__float_as_uint(__uint_as_float(r.x) * disl[dl]),
                               r.y >> BSH);
    }
}

// ---------------- finalize norm: *= dis[src]  (dis is L2-resident, 400KB) ----------------
__global__ __launch_bounds__(256) void k_norm(uint2* __restrict__ rec2,
                                              const float* __restrict__ dis) {
    int j = blockIdx.x * 256 + threadIdx.x;  // grid exact NE/256
    uint2 r = rec2[j];
    rec2[j] = make_uint2(__float_as_uint(__uint_as_float(r.x) * dis[r.y]), r.y);
}

// ---------------- h1 = x @ W1  (x:[NN,128], W1:[128,64]), 80-row tiles ----------------
#define XPAD 136
#define FMA4(a, s, b) { a.x = fmaf(s, b.x, a.x); a.y = fmaf(s, b.y, a.y); \
                        a.z = fmaf(s, b.z, a.z); a.w = fmaf(s, b.w, a.w); }

__global__ __launch_bounds__(320) void k_gemm1(const float* __restrict__ x,
                                               const float* __restrict__ W,
                                               float* __restrict__ h) {
    __shared__ float xs[80 * XPAD];
    __shared__ float Ws[128 * 64];
    int tid  = threadIdx.x;
    int row0 = blockIdx.x * 80;

    for (int j = tid; j < 2048; j += 320)
        ((float4*)Ws)[j] = ((const float4*)W)[j];
    for (int j = tid; j < 2560; j += 320) {
        int r = j >> 5, kq = j & 31;
        *(float4*)&xs[r * XPAD + kq * 4] =
            *(const float4*)&x[(row0 + r) * 128 + kq * 4];
    }
    __syncthreads();

    int cg = tid & 15, rg = tid >> 4;
    int c0 = cg * 4, r0 = rg * 4;

    float4 acc0 = {0,0,0,0}, acc1 = {0,0,0,0}, acc2 = {0,0,0,0}, acc3 = {0,0,0,0};
    #pragma unroll
    for (int kq = 0; kq < 32; ++kq) {
        float4 xv0 = *(const float4*)&xs[(r0 + 0) * XPAD + kq * 4];
        float4 xv1 = *(const float4*)&xs[(r0 + 1) * XPAD + kq * 4];
        float4 xv2 = *(const float4*)&xs[(r0 + 2) * XPAD + kq * 4];
        float4 xv3 = *(const float4*)&xs[(r0 + 3) * XPAD + kq * 4];
        float4 wv0 = *(const float4*)&Ws[(kq * 4 + 0) * 64 + c0];
        float4 wv1 = *(const float4*)&Ws[(kq * 4 + 1) * 64 + c0];
        float4 wv2 = *(const float4*)&Ws[(kq * 4 + 2) * 64 + c0];
        float4 wv3 = *(const float4*)&Ws[(kq * 4 + 3) * 64 + c0];
        FMA4(acc0, xv0.x, wv0); FMA4(acc0, xv0.y, wv1); FMA4(acc0, xv0.z, wv2); FMA4(acc0, xv0.w, wv3);
        FMA4(acc1, xv1.x, wv0); FMA4(acc1, xv1.y, wv1); FMA4(acc1, xv1.z, wv2); FMA4(acc1, xv1.w, wv3);
        FMA4(acc2, xv2.x, wv0); FMA4(acc2, xv2.y, wv1); FMA4(acc2, xv2.z, wv2); FMA4(acc2, xv2.w, wv3);
        FMA4(acc3, xv3.x, wv0); FMA4(acc3, xv3.y, wv1); FMA4(acc3, xv3.z, wv2); FMA4(acc3, xv3.w, wv3);
    }

    float* hp = h + (row0 + r0) * 64 + c0;
    *(float4*)(hp)       = acc0;
    *(float4*)(hp + 64)  = acc1;
    *(float4*)(hp + 128) = acc2;
    *(float4*)(hp + 192) = acc3;
}

// ---------------- layer-1 aggregation: one wave per node, lane = feature ----------------
__global__ __launch_bounds__(256) void k_agg1(const int* __restrict__ row_ptr,
                                              const uint2* __restrict__ rec2,
                                              const float* __restrict__ h1,
                                              const float* __restrict__ dis,
                                              const float* __restrict__ b1,
                                              float* __restrict__ xemb) {
    int n = (blockIdx.x * 256 + threadIdx.x) >> 6;  // grid exact: NN*64/256 blocks
    int f = threadIdx.x & 63;
    float di = dis[n];
    float acc = fmaf(di * di, h1[n * 64 + f], b1[f]);
    int j = row_ptr[n], end = row_ptr[n + 1];
    for (; j + 1 < end; j += 2) {   // 2-deep: two gathers in flight
        uint2 p0 = rec2[j], p1 = rec2[j + 1];
        float v0 = h1[p0.y * 64 + f];
        float v1 = h1[p1.y * 64 + f];
        acc = fmaf(__uint_as_float(p0.x), v0, acc);
        acc = fmaf(__uint_as_float(p1.x), v1, acc);
    }
    if (j < end) {
        uint2 p = rec2[j];
        acc = fmaf(__uint_as_float(p.x), h1[p.y * 64 + f], acc);
    }
    xemb[n * 64 + f] = acc;
}

// ---------------- h3 = relu(x_emb) @ W2   (W2:[64,16]) ----------------
__global__ __launch_bounds__(256) void k_gemm2(const float* __restrict__ xemb,
                                               const float* __restrict__ W,
                                               float* __restrict__ h3) {
    __shared__ float Ws[64 * 16];
    __shared__ float xs[16][65];
    int tid  = threadIdx.x;
    int row0 = blockIdx.x * 16;

    for (int i = tid; i < 64 * 16; i += 256) Ws[i] = W[i];
    for (int i = tid; i < 16 * 64; i += 256) {
        float v = xemb[row0 * 64 + i];
        xs[i >> 6][i & 63] = v > 0.0f ? v : 0.0f;  // fused ReLU
    }
    __syncthreads();

    int col = tid & 15, r = tid >> 4;
    float a = 0.f;
    #pragma unroll
    for (int k = 0; k < 64; ++k) a = fmaf(xs[r][k], Ws[k * 16 + col], a);
    h3[(row0 + r) * 16 + col] = a;
}

// ---------------- layer-2 aggregation: wave = node, 16 feats x 4 edge groups ----------------
__global__ __launch_bounds__(256) void k_agg2(const int* __restrict__ row_ptr,
                                              const uint2* __restrict__ rec2,
                                              const float* __restrict__ h3,
                                              const float* __restrict__ dis,
                                              const float* __restrict__ b2,
                                              float* __restrict__ out) {
    int n    = (blockIdx.x * 256 + threadIdx.x) >> 6;
    int lane = threadIdx.x & 63;
    int f = lane & 15, g = lane >> 4;
    int start = row_ptr[n], end = row_ptr[n + 1];
    float acc = 0.f;
    for (int j = start + g; j < end; j += 4) {
        uint2 p = rec2[j];
        acc = fmaf(__uint_as_float(p.x), h3[p.y * 16 + f], acc);
    }
    acc += __shfl_xor(acc, 16, 64);   // reduce the 4 edge groups
    acc += __shfl_xor(acc, 32, 64);
    if (g == 0) {
        float di = dis[n];
        out[n * 16 + f] = fmaf(di * di, h3[n * 16 + f], b2[f]) + acc;
    }
}

extern "C" void kernel_launch(void* const* d_in, const int* in_sizes, int n_in,
                              void* d_out, int out_size, void* d_ws, size_t ws_size,
                              hipStream_t stream) {
    const float* x  = (const float*)d_in[0];
    const int*   ei = (const int*)d_in[1];
    const float* w  = (const float*)d_in[2];
    const float* W1 = (const float*)d_in[3];
    const float* b1 = (const float*)d_in[4];
    const float* W2 = (const float*)d_in[5];
    const float* b2 = (const float*)d_in[6];
    const int* src = ei;
    const int* dst = ei + NE;

    float* out2 = (float*)d_out;               // [NN,16]  output 0
    float* xemb = (float*)d_out + NN * 16;     // [NN,64]  output 1

    // workspace (~46 MB): h1 ALIASES rec (rec dead after k_build, h1 born at k_gemm1)
    float* h1      = (float*)d_ws;                     // NN*64 fp32 = 25.6MB
    uint2* rec     = (uint2*)d_ws;                     // NE uint2  = 12.8MB (stage 1)
    uint2* rec2    = (uint2*)(h1 + (size_t)NN * 64);   // NE uint2  = 12.8MB (sorted CSR)
    float* h3      = (float*)(rec2 + NE);              // NN*16
    float* dis     = h3 + (size_t)NN * 16;             // NN
    int*   row_ptr = (int*)(dis + NN);                 // NN+1
    int*   bktcnt  = row_ptr + NN + 2;                 // NBKT
    int*   bktbase = bktcnt + NBKT;                    // NBKT+1
    int*   cursor  = bktbase + NBKT + 1;               // NBKT

    // --- build (shared by both layers) ---
    k_zero <<<(NBKT + 255) / 256, 256, 0, stream>>>(bktcnt);
    k_hist <<<NPB,  256, 0, stream>>>(dst, bktcnt);
    k_scan <<<1,   1024, 0, stream>>>(bktcnt, bktbase, cursor, row_ptr);
    k_part <<<NPB,  256, 0, stream>>>(src, dst, w, cursor, rec);
    k_build<<<NBKT, 256, 0, stream>>>(bktbase, rec, rec2, dis, row_ptr);
    k_norm <<<NE / 256, 256, 0, stream>>>(rec2, dis);

    // --- layer 1 ---
    k_gemm1<<<NN / 80, 320, 0, stream>>>(x, W1, h1);
    k_agg1 <<<NN * 64 / 256, 256, 0, stream>>>(row_ptr, rec2, h1, dis, b1, xemb);

    // --- layer 2 ---
    k_gemm2<<<NN / 16, 256, 0, stream>>>(xemb, W2, h3);
    k_agg2 <<<NN * 64 / 256, 256, 0, stream>>>(row_ptr, rec2, h3, dis, b2, out2);
}

// Round 6
// 248.308 us; speedup vs baseline: 3.9699x; 1.1917x over previous
//
#include <hip/hip_runtime.h>

#define NN 100000
#define NE 1600000
#define BSH 7                 // log2(nodes per bucket)
#define BSZ 128               // nodes per bucket
#define NBKT 782              // ceil(NN/BSZ)
#define NPB 256               // partition blocks
#define EPB 6250              // edges per partition block (NE/NPB, exact)

typedef unsigned short u16;
typedef unsigned int   u32;

__device__ __forceinline__ float bf2f(u16 u) {
    union { u32 i; float f; } v; v.i = ((u32)u) << 16; return v.f;
}
__device__ __forceinline__ u16 f2bf(float f) {
    union { float f; u32 i; } v; v.f = f;
    u32 u = v.i;
    u += 0x7FFFu + ((u >> 16) & 1);   // round-to-nearest-even
    return (u16)(u >> 16);
}

// ---------------- zero bucket counters ----------------
__global__ __launch_bounds__(256) void k_zero(int* __restrict__ bktcnt) {
    int i = blockIdx.x * 256 + threadIdx.x;
    if (i < NBKT) bktcnt[i] = 0;
}

// ---------------- bucket histogram (LDS-privatized) ----------------
__global__ __launch_bounds__(256) void k_hist(const int* __restrict__ dst,
                                              int* __restrict__ bktcnt) {
    __shared__ int cnt[NBKT];
    int tid = threadIdx.x;
    for (int i = tid; i < NBKT; i += 256) cnt[i] = 0;
    __syncthreads();
    int e0 = blockIdx.x * EPB;
    for (int j = tid; j < EPB; j += 256)
        atomicAdd(&cnt[dst[e0 + j] >> BSH], 1);
    __syncthreads();
    for (int i = tid; i < NBKT; i += 256)
        if (cnt[i]) atomicAdd(&bktcnt[i], cnt[i]);
}

// ---------------- scan 782 bucket counts ----------------
__global__ __launch_bounds__(1024) void k_scan(const int* __restrict__ bktcnt,
                                               int* __restrict__ bktbase,
                                               int* __restrict__ cursor,
                                               int* __restrict__ row_ptr) {
    __shared__ int s[1024];
    int t = threadIdx.x;
    s[t] = (t < NBKT) ? bktcnt[t] : 0;
    __syncthreads();
    #pragma unroll
    for (int off = 1; off < 1024; off <<= 1) {
        int add = (t >= off) ? s[t - off] : 0;
        __syncthreads();
        s[t] += add;
        __syncthreads();
    }
    if (t < NBKT) {
        int b = (t == 0) ? 0 : s[t - 1];
        bktbase[t] = b;
        cursor[t]  = b;
    }
    if (t == 0) { bktbase[NBKT] = NE; row_ptr[NN] = NE; }
}

// ---------------- partition edges into buckets: rec = (w_bits, src<<7|dstLo) ----------------
__global__ __launch_bounds__(256) void k_part(const int* __restrict__ src,
                                              const int* __restrict__ dst,
                                              const float* __restrict__ w,
                                              int* __restrict__ cursor,
                                              uint2* __restrict__ rec) {
    __shared__ int cnt[NBKT];
    __shared__ int base[NBKT];
    int tid = threadIdx.x;
    for (int i = tid; i < NBKT; i += 256) cnt[i] = 0;
    __syncthreads();
    int e0 = blockIdx.x * EPB;
    for (int j = tid; j < EPB; j += 256)
        atomicAdd(&cnt[dst[e0 + j] >> BSH], 1);
    __syncthreads();
    for (int i = tid; i < NBKT; i += 256) {
        int c = cnt[i];
        base[i] = c ? atomicAdd(&cursor[i], c) : 0;  // one global atomic per (block,bucket)
    }
    __syncthreads();
    for (int i = tid; i < NBKT; i += 256) cnt[i] = 0;
    __syncthreads();
    for (int j = tid; j < EPB; j += 256) {
        int e  = e0 + j;
        int d  = dst[e];
        int bk = d >> BSH;
        int slot = base[bk] + atomicAdd(&cnt[bk], 1);   // LDS cursor
        rec[slot] = make_uint2(__float_as_uint(w[e]),
                               ((u32)src[e] << BSH) | (u32)(d & (BSZ - 1)));
    }
}

// ---------------- per-bucket: deg -> dis, counting-sort to per-node CSR ----------------
// rec2[pos] = (w * dis[dst], src) sorted by dst; row_ptr[node] = start
__global__ __launch_bounds__(256) void k_build(const int* __restrict__ bktbase,
                                               const uint2* __restrict__ rec,
                                               uint2* __restrict__ rec2,
                                               float* __restrict__ dis,
                                               int* __restrict__ row_ptr) {
    __shared__ float dw[BSZ];
    __shared__ int   cnt[BSZ];
    __shared__ int   base[BSZ];
    __shared__ int   scn[BSZ];
    __shared__ float disl[BSZ];
    int b = blockIdx.x, tid = threadIdx.x;
    int s = bktbase[b], e = bktbase[b + 1];
    if (tid < BSZ) { dw[tid] = 1.0f; cnt[tid] = 0; }   // self-loop weight
    __syncthreads();
    for (int j = s + tid; j < e; j += 256) {
        uint2 r = rec[j];
        int dl = r.y & (BSZ - 1);
        atomicAdd(&cnt[dl], 1);
        atomicAdd(&dw[dl], __uint_as_float(r.x));
    }
    __syncthreads();
    if (tid < BSZ) scn[tid] = cnt[tid];
    __syncthreads();
    #pragma unroll
    for (int off = 1; off < BSZ; off <<= 1) {          // Hillis-Steele over 128
        int add = (tid < BSZ && tid >= off) ? scn[tid - off] : 0;
        __syncthreads();
        if (tid < BSZ) scn[tid] += add;
        __syncthreads();
    }
    if (tid < BSZ) {
        int node = b * BSZ + tid;
        base[tid] = (tid == 0) ? 0 : scn[tid - 1];
        float d = rsqrtf(dw[tid]);                     // dw >= 1 always
        disl[tid] = d;
        if (node < NN) { dis[node] = d; row_ptr[node] = s + base[tid]; }
        cnt[tid] = 0;                                   // reuse as cursor
    }
    __syncthreads();
    for (int j = s + tid; j < e; j += 256) {
        uint2 r = rec[j];
        int dl = r.y & (BSZ - 1);
        int pos = s + base[dl] + atomicAdd(&cnt[dl], 1);
        rec2[pos] = make_uint2(__float_as_uint(__uint_as_float(r.x) * disl[dl]),
                               r.y >> BSH);
    }
}

// ---------------- h1b = bf16(dis * (x @ W1))  (x:[NN,128], W1:[128,64]) ----------------
#define XPAD 136
#define FMA4(a, s, b) { a.x = fmaf(s, b.x, a.x); a.y = fmaf(s, b.y, a.y); \
                        a.z = fmaf(s, b.z, a.z); a.w = fmaf(s, b.w, a.w); }

__global__ __launch_bounds__(320) void k_gemm1(const float* __restrict__ x,
                                               const float* __restrict__ W,
                                               const float* __restrict__ dis,
                                               u16* __restrict__ h1b) {
    __shared__ float xs[80 * XPAD];
    __shared__ float Ws[128 * 64];
    int tid  = threadIdx.x;
    int row0 = blockIdx.x * 80;

    for (int j = tid; j < 2048; j += 320)
        ((float4*)Ws)[j] = ((const float4*)W)[j];
    for (int j = tid; j < 2560; j += 320) {
        int r = j >> 5, kq = j & 31;
        *(float4*)&xs[r * XPAD + kq * 4] =
            *(const float4*)&x[(row0 + r) * 128 + kq * 4];
    }
    __syncthreads();

    int cg = tid & 15, rg = tid >> 4;
    int c0 = cg * 4, r0 = rg * 4;

    float4 acc0 = {0,0,0,0}, acc1 = {0,0,0,0}, acc2 = {0,0,0,0}, acc3 = {0,0,0,0};
    #pragma unroll
    for (int kq = 0; kq < 32; ++kq) {
        float4 xv0 = *(const float4*)&xs[(r0 + 0) * XPAD + kq * 4];
        float4 xv1 = *(const float4*)&xs[(r0 + 1) * XPAD + kq * 4];
        float4 xv2 = *(const float4*)&xs[(r0 + 2) * XPAD + kq * 4];
        float4 xv3 = *(const float4*)&xs[(r0 + 3) * XPAD + kq * 4];
        float4 wv0 = *(const float4*)&Ws[(kq * 4 + 0) * 64 + c0];
        float4 wv1 = *(const float4*)&Ws[(kq * 4 + 1) * 64 + c0];
        float4 wv2 = *(const float4*)&Ws[(kq * 4 + 2) * 64 + c0];
        float4 wv3 = *(const float4*)&Ws[(kq * 4 + 3) * 64 + c0];
        FMA4(acc0, xv0.x, wv0); FMA4(acc0, xv0.y, wv1); FMA4(acc0, xv0.z, wv2); FMA4(acc0, xv0.w, wv3);
        FMA4(acc1, xv1.x, wv0); FMA4(acc1, xv1.y, wv1); FMA4(acc1, xv1.z, wv2); FMA4(acc1, xv1.w, wv3);
        FMA4(acc2, xv2.x, wv0); FMA4(acc2, xv2.y, wv1); FMA4(acc2, xv2.z, wv2); FMA4(acc2, xv2.w, wv3);
        FMA4(acc3, xv3.x, wv0); FMA4(acc3, xv3.y, wv1); FMA4(acc3, xv3.z, wv2); FMA4(acc3, xv3.w, wv3);
    }

    int r = row0 + r0;
    float d0 = dis[r], d1 = dis[r + 1], d2 = dis[r + 2], d3 = dis[r + 3];
    ushort4 s0 = { f2bf(acc0.x * d0), f2bf(acc0.y * d0), f2bf(acc0.z * d0), f2bf(acc0.w * d0) };
    ushort4 s1 = { f2bf(acc1.x * d1), f2bf(acc1.y * d1), f2bf(acc1.z * d1), f2bf(acc1.w * d1) };
    ushort4 s2 = { f2bf(acc2.x * d2), f2bf(acc2.y * d2), f2bf(acc2.z * d2), f2bf(acc2.w * d2) };
    ushort4 s3 = { f2bf(acc3.x * d3), f2bf(acc3.y * d3), f2bf(acc3.z * d3), f2bf(acc3.w * d3) };
    u16* hp = h1b + (size_t)r * 64 + c0;
    *(ushort4*)(hp)       = s0;
    *(ushort4*)(hp + 64)  = s1;
    *(ushort4*)(hp + 128) = s2;
    *(ushort4*)(hp + 192) = s3;
}

// ---------------- layer-1 aggregation: one wave per node, lane = feature ----------------
__global__ __launch_bounds__(256) void k_agg1(const int* __restrict__ row_ptr,
                                              const uint2* __restrict__ rec2,
                                              const u16* __restrict__ h1b,
                                              const float* __restrict__ dis,
                                              const float* __restrict__ b1,
                                              float* __restrict__ xemb) {
    int n = (blockIdx.x * 256 + threadIdx.x) >> 6;
    int f = threadIdx.x & 63;
    float di = dis[n];
    float acc = fmaf(di, bf2f(h1b[(size_t)n * 64 + f]), b1[f]);  // self-loop: dis^2*h1 = dis*h1b
    int j = row_ptr[n], end = row_ptr[n + 1];
    for (; j + 3 < end; j += 4) {   // 4-deep: four gathers in flight
        uint2 p0 = rec2[j], p1 = rec2[j + 1], p2 = rec2[j + 2], p3 = rec2[j + 3];
        float v0 = bf2f(h1b[(size_t)p0.y * 64 + f]);
        float v1 = bf2f(h1b[(size_t)p1.y * 64 + f]);
        float v2 = bf2f(h1b[(size_t)p2.y * 64 + f]);
        float v3 = bf2f(h1b[(size_t)p3.y * 64 + f]);
        acc = fmaf(__uint_as_float(p0.x), v0, acc);
        acc = fmaf(__uint_as_float(p1.x), v1, acc);
        acc = fmaf(__uint_as_float(p2.x), v2, acc);
        acc = fmaf(__uint_as_float(p3.x), v3, acc);
    }
    for (; j < end; ++j) {
        uint2 p = rec2[j];
        acc = fmaf(__uint_as_float(p.x), bf2f(h1b[(size_t)p.y * 64 + f]), acc);
    }
    xemb[(size_t)n * 64 + f] = acc;
}

// ---------------- h3b = bf16(dis * (relu(xemb) @ W2))   (W2:[64,16]) ----------------
__global__ __launch_bounds__(256) void k_gemm2(const float* __restrict__ xemb,
                                               const float* __restrict__ W,
                                               const float* __restrict__ dis,
                                               u16* __restrict__ h3b) {
    __shared__ float Ws[64 * 16];
    __shared__ float xs[16][65];
    int tid  = threadIdx.x;
    int row0 = blockIdx.x * 16;

    for (int i = tid; i < 64 * 16; i += 256) Ws[i] = W[i];
    for (int i = tid; i < 16 * 64; i += 256) {
        float v = xemb[(size_t)row0 * 64 + i];
        xs[i >> 6][i & 63] = v > 0.0f ? v : 0.0f;  // fused ReLU
    }
    __syncthreads();

    int col = tid & 15, r = tid >> 4;
    float a = 0.f;
    #pragma unroll
    for (int k = 0; k < 64; ++k) a = fmaf(xs[r][k], Ws[k * 16 + col], a);
    h3b[(size_t)(row0 + r) * 16 + col] = f2bf(a * dis[row0 + r]);
}

// ---------------- layer-2 aggregation: wave = node, 16 feats x 4 edge groups ----------------
__global__ __launch_bounds__(256) void k_agg2(const int* __restrict__ row_ptr,
                                              const uint2* __restrict__ rec2,
                                              const u16* __restrict__ h3b,
                                              const float* __restrict__ dis,
                                              const float* __restrict__ b2,
                                              float* __restrict__ out) {
    int n    = (blockIdx.x * 256 + threadIdx.x) >> 6;
    int lane = threadIdx.x & 63;
    int f = lane & 15, g = lane >> 4;
    int start = row_ptr[n], end = row_ptr[n + 1];
    float acc = 0.f;
    int j = start + g;
    for (; j + 4 < end; j += 8) {     // 2 per group in flight
        uint2 p0 = rec2[j], p1 = rec2[j + 4];
        float v0 = bf2f(h3b[(size_t)p0.y * 16 + f]);
        float v1 = bf2f(h3b[(size_t)p1.y * 16 + f]);
        acc = fmaf(__uint_as_float(p0.x), v0, acc);
        acc = fmaf(__uint_as_float(p1.x), v1, acc);
    }
    if (j < end) {
        uint2 p = rec2[j];
        acc = fmaf(__uint_as_float(p.x), bf2f(h3b[(size_t)p.y * 16 + f]), acc);
    }
    acc += __shfl_xor(acc, 16, 64);   // reduce the 4 edge groups
    acc += __shfl_xor(acc, 32, 64);
    if (g == 0) {
        float di = dis[n];
        out[(size_t)n * 16 + f] = fmaf(di, bf2f(h3b[(size_t)n * 16 + f]), b2[f]) + acc;
    }
}

extern "C" void kernel_launch(void* const* d_in, const int* in_sizes, int n_in,
                              void* d_out, int out_size, void* d_ws, size_t ws_size,
                              hipStream_t stream) {
    const float* x  = (const float*)d_in[0];
    const int*   ei = (const int*)d_in[1];
    const float* w  = (const float*)d_in[2];
    const float* W1 = (const float*)d_in[3];
    const float* b1 = (const float*)d_in[4];
    const float* W2 = (const float*)d_in[5];
    const float* b2 = (const float*)d_in[6];
    const int* src = ei;
    const int* dst = ei + NE;

    float* out2 = (float*)d_out;               // [NN,16]  output 0
    float* xemb = (float*)d_out + NN * 16;     // [NN,64]  output 1

    // workspace (~30 MB): h1b ALIASES rec (rec dead after k_build, h1b born at k_gemm1)
    uint2* rec     = (uint2*)d_ws;                     // NE uint2 = 12.8MB (stage 1)
    u16*   h1b     = (u16*)d_ws;                       // NN*64 u16 = 12.8MB (alias)
    uint2* rec2    = (uint2*)((char*)d_ws + (size_t)NE * 8);  // NE uint2 = 12.8MB
    u16*   h3b     = (u16*)(rec2 + NE);                // NN*16 u16 = 3.2MB
    float* dis     = (float*)(h3b + (size_t)NN * 16);  // NN
    int*   row_ptr = (int*)(dis + NN);                 // NN+1
    int*   bktcnt  = row_ptr + NN + 2;                 // NBKT
    int*   bktbase = bktcnt + NBKT;                    // NBKT+1
    int*   cursor  = bktbase + NBKT + 1;               // NBKT

    // --- build (shared by both layers) ---
    k_zero <<<(NBKT + 255) / 256, 256, 0, stream>>>(bktcnt);
    k_hist <<<NPB,  256, 0, stream>>>(dst, bktcnt);
    k_scan <<<1,   1024, 0, stream>>>(bktcnt, bktbase, cursor, row_ptr);
    k_part <<<NPB,  256, 0, stream>>>(src, dst, w, cursor, rec);
    k_build<<<NBKT, 256, 0, stream>>>(bktbase, rec, rec2, dis, row_ptr);

    // --- layer 1 ---
    k_gemm1<<<NN / 80, 320, 0, stream>>>(x, W1, dis, h1b);
    k_agg1 <<<NN * 64 / 256, 256, 0, stream>>>(row_ptr, rec2, h1b, dis, b1, xemb);

    // --- layer 2 ---
    k_gemm2<<<NN / 16, 256, 0, stream>>>(xemb, W2, dis, h3b);
    k_agg2 <<<NN * 64 / 256, 256, 0, stream>>>(row_ptr, rec2, h3b, dis, b2, out2);
}

// Round 7
// 236.653 us; speedup vs baseline: 4.1654x; 1.0493x over previous
//
#include <hip/hip_runtime.h>

#define NN 100000
#define NE 1600000
#define BSH 7                 // log2(nodes per bucket)
#define BSZ 128               // nodes per bucket
#define NBKT 782              // ceil(NN/BSZ)
#define NPB 256               // partition blocks
#define EPB 6250              // edges per partition block (NE/NPB, exact)

typedef unsigned short u16;
typedef unsigned int   u32;

__device__ __forceinline__ float bf2f(u16 u) {
    union { u32 i; float f; } v; v.i = ((u32)u) << 16; return v.f;
}
__device__ __forceinline__ u16 f2bf(float f) {
    union { float f; u32 i; } v; v.f = f;
    u32 u = v.i;
    u += 0x7FFFu + ((u >> 16) & 1);   // round-to-nearest-even
    return (u16)(u >> 16);
}

// ---------------- zero bucket counters ----------------
__global__ __launch_bounds__(256) void k_zero(int* __restrict__ bktcnt) {
    int i = blockIdx.x * 256 + threadIdx.x;
    if (i < NBKT) bktcnt[i] = 0;
}

// ---------------- bucket histogram (LDS-privatized) ----------------
__global__ __launch_bounds__(256) void k_hist(const int* __restrict__ dst,
                                              int* __restrict__ bktcnt) {
    __shared__ int cnt[NBKT];
    int tid = threadIdx.x;
    for (int i = tid; i < NBKT; i += 256) cnt[i] = 0;
    __syncthreads();
    int e0 = blockIdx.x * EPB;
    for (int j = tid; j < EPB; j += 256)
        atomicAdd(&cnt[dst[e0 + j] >> BSH], 1);
    __syncthreads();
    for (int i = tid; i < NBKT; i += 256)
        if (cnt[i]) atomicAdd(&bktcnt[i], cnt[i]);
}

// ---------------- scan 782 bucket counts ----------------
__global__ __launch_bounds__(1024) void k_scan(const int* __restrict__ bktcnt,
                                               int* __restrict__ bktbase,
                                               int* __restrict__ cursor,
                                               int* __restrict__ row_ptr) {
    __shared__ int s[1024];
    int t = threadIdx.x;
    s[t] = (t < NBKT) ? bktcnt[t] : 0;
    __syncthreads();
    #pragma unroll
    for (int off = 1; off < 1024; off <<= 1) {
        int add = (t >= off) ? s[t - off] : 0;
        __syncthreads();
        s[t] += add;
        __syncthreads();
    }
    if (t < NBKT) {
        int b = (t == 0) ? 0 : s[t - 1];
        bktbase[t] = b;
        cursor[t]  = b;
    }
    if (t == 0) { bktbase[NBKT] = NE; row_ptr[NN] = NE; }
}

// ---------------- partition edges into buckets: rec = (w_bits, src<<7|dstLo) ----------------
__global__ __launch_bounds__(256) void k_part(const int* __restrict__ src,
                                              const int* __restrict__ dst,
                                              const float* __restrict__ w,
                                              int* __restrict__ cursor,
                                              uint2* __restrict__ rec) {
    __shared__ int cnt[NBKT];
    __shared__ int base[NBKT];
    int tid = threadIdx.x;
    for (int i = tid; i < NBKT; i += 256) cnt[i] = 0;
    __syncthreads();
    int e0 = blockIdx.x * EPB;
    for (int j = tid; j < EPB; j += 256)
        atomicAdd(&cnt[dst[e0 + j] >> BSH], 1);
    __syncthreads();
    for (int i = tid; i < NBKT; i += 256) {
        int c = cnt[i];
        base[i] = c ? atomicAdd(&cursor[i], c) : 0;  // one global atomic per (block,bucket)
    }
    __syncthreads();
    for (int i = tid; i < NBKT; i += 256) cnt[i] = 0;
    __syncthreads();
    for (int j = tid; j < EPB; j += 256) {
        int e  = e0 + j;
        int d  = dst[e];
        int bk = d >> BSH;
        int slot = base[bk] + atomicAdd(&cnt[bk], 1);   // LDS cursor
        rec[slot] = make_uint2(__float_as_uint(w[e]),
                               ((u32)src[e] << BSH) | (u32)(d & (BSZ - 1)));
    }
}

// ---------------- per-bucket: deg -> dis, counting-sort to per-node CSR ----------------
// rec2[pos] = (w * dis[dst], src) sorted by dst; row_ptr[node] = start
__global__ __launch_bounds__(256) void k_build(const int* __restrict__ bktbase,
                                               const uint2* __restrict__ rec,
                                               uint2* __restrict__ rec2,
                                               float* __restrict__ dis,
                                               int* __restrict__ row_ptr) {
    __shared__ float dw[BSZ];
    __shared__ int   cnt[BSZ];
    __shared__ int   base[BSZ];
    __shared__ int   scn[BSZ];
    __shared__ float disl[BSZ];
    int b = blockIdx.x, tid = threadIdx.x;
    int s = bktbase[b], e = bktbase[b + 1];
    if (tid < BSZ) { dw[tid] = 1.0f; cnt[tid] = 0; }   // self-loop weight
    __syncthreads();
    for (int j = s + tid; j < e; j += 256) {
        uint2 r = rec[j];
        int dl = r.y & (BSZ - 1);
        atomicAdd(&cnt[dl], 1);
        atomicAdd(&dw[dl], __uint_as_float(r.x));
    }
    __syncthreads();
    if (tid < BSZ) scn[tid] = cnt[tid];
    __syncthreads();
    #pragma unroll
    for (int off = 1; off < BSZ; off <<= 1) {          // Hillis-Steele over 128
        int add = (tid < BSZ && tid >= off) ? scn[tid - off] : 0;
        __syncthreads();
        if (tid < BSZ) scn[tid] += add;
        __syncthreads();
    }
    if (tid < BSZ) {
        int node = b * BSZ + tid;
        base[tid] = (tid == 0) ? 0 : scn[tid - 1];
        float d = rsqrtf(dw[tid]);                     // dw >= 1 always
        disl[tid] = d;
        if (node < NN) { dis[node] = d; row_ptr[node] = s + base[tid]; }
        cnt[tid] = 0;                                   // reuse as cursor
    }
    __syncthreads();
    for (int j = s + tid; j < e; j += 256) {
        uint2 r = rec[j];
        int dl = r.y & (BSZ - 1);
        int pos = s + base[dl] + atomicAdd(&cnt[dl], 1);
        rec2[pos] = make_uint2(__float_as_uint(__uint_as_float(r.x) * disl[dl]),
                               r.y >> BSH);
    }
}

// ---------------- h1b = bf16(dis * (x @ W1)) ----------------
// LDS = W1 only (32KB). 8 waves/block, 4 rows/wave, lane = col.
// x reads are wave-uniform (scalar path); occupancy 4 blocks/CU = 32 waves.
__global__ __launch_bounds__(512) void k_gemm1(const float* __restrict__ x,
                                               const float* __restrict__ W,
                                               const float* __restrict__ dis,
                                               u16* __restrict__ h1b) {
    __shared__ float Ws[128 * 64];   // [k][col], 32 KB
    int tid = threadIdx.x;
    for (int j = tid; j < 2048; j += 512)
        ((float4*)Ws)[j] = ((const float4*)W)[j];
    __syncthreads();

    int wave = __builtin_amdgcn_readfirstlane(tid >> 6);  // scalar wave id
    int lane = tid & 63;                                  // output column
    int r0   = blockIdx.x * 32 + wave * 4;                // 4 rows per wave (3125*32 = NN)
    const float* xp = x + (size_t)r0 * 128;

    float a0 = 0.f, a1 = 0.f, a2 = 0.f, a3 = 0.f;
    #pragma unroll 4
    for (int kq = 0; kq < 32; ++kq) {
        float4 x0 = *(const float4*)&xp[0 * 128 + kq * 4];   // wave-uniform
        float4 x1 = *(const float4*)&xp[1 * 128 + kq * 4];
        float4 x2 = *(const float4*)&xp[2 * 128 + kq * 4];
        float4 x3 = *(const float4*)&xp[3 * 128 + kq * 4];
        float w0 = Ws[(kq * 4 + 0) * 64 + lane];             // 2-way bank alias: free
        float w1 = Ws[(kq * 4 + 1) * 64 + lane];
        float w2 = Ws[(kq * 4 + 2) * 64 + lane];
        float w3 = Ws[(kq * 4 + 3) * 64 + lane];
        a0 = fmaf(x0.x, w0, a0); a0 = fmaf(x0.y, w1, a0); a0 = fmaf(x0.z, w2, a0); a0 = fmaf(x0.w, w3, a0);
        a1 = fmaf(x1.x, w0, a1); a1 = fmaf(x1.y, w1, a1); a1 = fmaf(x1.z, w2, a1); a1 = fmaf(x1.w, w3, a1);
        a2 = fmaf(x2.x, w0, a2); a2 = fmaf(x2.y, w1, a2); a2 = fmaf(x2.z, w2, a2); a2 = fmaf(x2.w, w3, a2);
        a3 = fmaf(x3.x, w0, a3); a3 = fmaf(x3.y, w1, a3); a3 = fmaf(x3.z, w2, a3); a3 = fmaf(x3.w, w3, a3);
    }

    float d0 = dis[r0], d1 = dis[r0 + 1], d2 = dis[r0 + 2], d3 = dis[r0 + 3];
    u16* hp = h1b + (size_t)r0 * 64 + lane;
    hp[0]   = f2bf(a0 * d0);
    hp[64]  = f2bf(a1 * d1);
    hp[128] = f2bf(a2 * d2);
    hp[192] = f2bf(a3 * d3);
}

// ---------------- layer-1 aggregation: one wave per node, lane = feature ----------------
__global__ __launch_bounds__(256) void k_agg1(const int* __restrict__ row_ptr,
                                              const uint2* __restrict__ rec2,
                                              const u16* __restrict__ h1b,
                                              const float* __restrict__ dis,
                                              const float* __restrict__ b1,
                                              float* __restrict__ xemb) {
    int n = (blockIdx.x * 256 + threadIdx.x) >> 6;
    int f = threadIdx.x & 63;
    float di = dis[n];
    float acc = fmaf(di, bf2f(h1b[(size_t)n * 64 + f]), b1[f]);  // self-loop: dis^2*h1 = dis*h1b
    int j = row_ptr[n], end = row_ptr[n + 1];
    for (; j + 7 < end; j += 8) {   // 8-deep: eight gathers in flight
        uint2 p0 = rec2[j],     p1 = rec2[j + 1], p2 = rec2[j + 2], p3 = rec2[j + 3];
        uint2 p4 = rec2[j + 4], p5 = rec2[j + 5], p6 = rec2[j + 6], p7 = rec2[j + 7];
        float v0 = bf2f(h1b[(size_t)p0.y * 64 + f]);
        float v1 = bf2f(h1b[(size_t)p1.y * 64 + f]);
        float v2 = bf2f(h1b[(size_t)p2.y * 64 + f]);
        float v3 = bf2f(h1b[(size_t)p3.y * 64 + f]);
        float v4 = bf2f(h1b[(size_t)p4.y * 64 + f]);
        float v5 = bf2f(h1b[(size_t)p5.y * 64 + f]);
        float v6 = bf2f(h1b[(size_t)p6.y * 64 + f]);
        float v7 = bf2f(h1b[(size_t)p7.y * 64 + f]);
        acc = fmaf(__uint_as_float(p0.x), v0, acc);
        acc = fmaf(__uint_as_float(p1.x), v1, acc);
        acc = fmaf(__uint_as_float(p2.x), v2, acc);
        acc = fmaf(__uint_as_float(p3.x), v3, acc);
        acc = fmaf(__uint_as_float(p4.x), v4, acc);
        acc = fmaf(__uint_as_float(p5.x), v5, acc);
        acc = fmaf(__uint_as_float(p6.x), v6, acc);
        acc = fmaf(__uint_as_float(p7.x), v7, acc);
    }
    for (; j + 1 < end; j += 2) {
        uint2 p0 = rec2[j], p1 = rec2[j + 1];
        float v0 = bf2f(h1b[(size_t)p0.y * 64 + f]);
        float v1 = bf2f(h1b[(size_t)p1.y * 64 + f]);
        acc = fmaf(__uint_as_float(p0.x), v0, acc);
        acc = fmaf(__uint_as_float(p1.x), v1, acc);
    }
    if (j < end) {
        uint2 p = rec2[j];
        acc = fmaf(__uint_as_float(p.x), bf2f(h1b[(size_t)p.y * 64 + f]), acc);
    }
    xemb[(size_t)n * 64 + f] = acc;
}

// ---------------- h3b = bf16(dis * (relu(xemb) @ W2))   (W2:[64,16]) ----------------
__global__ __launch_bounds__(256) void k_gemm2(const float* __restrict__ xemb,
                                               const float* __restrict__ W,
                                               const float* __restrict__ dis,
                                               u16* __restrict__ h3b) {
    __shared__ float Ws[64 * 16];
    __shared__ float xs[16][65];
    int tid  = threadIdx.x;
    int row0 = blockIdx.x * 16;

    for (int i = tid; i < 64 * 16; i += 256) Ws[i] = W[i];
    for (int i = tid; i < 16 * 64; i += 256) {
        float v = xemb[(size_t)row0 * 64 + i];
        xs[i >> 6][i & 63] = v > 0.0f ? v : 0.0f;  // fused ReLU
    }
    __syncthreads();

    int col = tid & 15, r = tid >> 4;
    float a = 0.f;
    #pragma unroll
    for (int k = 0; k < 64; ++k) a = fmaf(xs[r][k], Ws[k * 16 + col], a);
    h3b[(size_t)(row0 + r) * 16 + col] = f2bf(a * dis[row0 + r]);
}

// ---------------- layer-2 aggregation: wave = node, 16 feats x 4 edge groups ----------------
__global__ __launch_bounds__(256) void k_agg2(const int* __restrict__ row_ptr,
                                              const uint2* __restrict__ rec2,
                                              const u16* __restrict__ h3b,
                                              const float* __restrict__ dis,
                                              const float* __restrict__ b2,
                                              float* __restrict__ out) {
    int n    = (blockIdx.x * 256 + threadIdx.x) >> 6;
    int lane = threadIdx.x & 63;
    int f = lane & 15, g = lane >> 4;
    int start = row_ptr[n], end = row_ptr[n + 1];
    float acc = 0.f;
    int j = start + g;
    for (; j + 4 < end; j += 8) {     // 2 per group in flight
        uint2 p0 = rec2[j], p1 = rec2[j + 4];
        float v0 = bf2f(h3b[(size_t)p0.y * 16 + f]);
        float v1 = bf2f(h3b[(size_t)p1.y * 16 + f]);
        acc = fmaf(__uint_as_float(p0.x), v0, acc);
        acc = fmaf(__uint_as_float(p1.x), v1, acc);
    }
    if (j < end) {
        uint2 p = rec2[j];
        acc = fmaf(__uint_as_float(p.x), bf2f(h3b[(size_t)p.y * 16 + f]), acc);
    }
    acc += __shfl_xor(acc, 16, 64);   // reduce the 4 edge groups
    acc += __shfl_xor(acc, 32, 64);
    if (g == 0) {
        float di = dis[n];
        out[(size_t)n * 16 + f] = fmaf(di, bf2f(h3b[(size_t)n * 16 + f]), b2[f]) + acc;
    }
}

extern "C" void kernel_launch(void* const* d_in, const int* in_sizes, int n_in,
                              void* d_out, int out_size, void* d_ws, size_t ws_size,
                              hipStream_t stream) {
    const float* x  = (const float*)d_in[0];
    const int*   ei = (const int*)d_in[1];
    const float* w  = (const float*)d_in[2];
    const float* W1 = (const float*)d_in[3];
    const float* b1 = (const float*)d_in[4];
    const float* W2 = (const float*)d_in[5];
    const float* b2 = (const float*)d_in[6];
    const int* src = ei;
    const int* dst = ei + NE;

    float* out2 = (float*)d_out;               // [NN,16]  output 0
    float* xemb = (float*)d_out + NN * 16;     // [NN,64]  output 1

    // workspace (~30 MB): h1b ALIASES rec (rec dead after k_build, h1b born at k_gemm1)
    uint2* rec     = (uint2*)d_ws;                     // NE uint2 = 12.8MB (stage 1)
    u16*   h1b     = (u16*)d_ws;                       // NN*64 u16 = 12.8MB (alias)
    uint2* rec2    = (uint2*)((char*)d_ws + (size_t)NE * 8);  // NE uint2 = 12.8MB
    u16*   h3b     = (u16*)(rec2 + NE);                // NN*16 u16 = 3.2MB
    float* dis     = (float*)(h3b + (size_t)NN * 16);  // NN
    int*   row_ptr = (int*)(dis + NN);                 // NN+1
    int*   bktcnt  = row_ptr + NN + 2;                 // NBKT
    int*   bktbase = bktcnt + NBKT;                    // NBKT+1
    int*   cursor  = bktbase + NBKT + 1;               // NBKT

    // --- build (shared by both layers) ---
    k_zero <<<(NBKT + 255) / 256, 256, 0, stream>>>(bktcnt);
    k_hist <<<NPB,  256, 0, stream>>>(dst, bktcnt);
    k_scan <<<1,   1024, 0, stream>>>(bktcnt, bktbase, cursor, row_ptr);
    k_part <<<NPB,  256, 0, stream>>>(src, dst, w, cursor, rec);
    k_build<<<NBKT, 256, 0, stream>>>(bktbase, rec, rec2, dis, row_ptr);

    // --- layer 1 ---
    k_gemm1<<<NN / 32, 512, 0, stream>>>(x, W1, dis, h1b);
    k_agg1 <<<NN * 64 / 256, 256, 0, stream>>>(row_ptr, rec2, h1b, dis, b1, xemb);

    // --- layer 2 ---
    k_gemm2<<<NN / 16, 256, 0, stream>>>(xemb, W2, dis, h3b);
    k_agg2 <<<NN * 64 / 256, 256, 0, stream>>>(row_ptr, rec2, h3b, dis, b2, out2);
}

// Round 8
// 200.621 us; speedup vs baseline: 4.9135x; 1.1796x over previous
//
#include <hip/hip_runtime.h>

#define NN 100000
#define NE 1600000
#define BSH 7                 // log2(nodes per bucket)
#define BSZ 128               // nodes per bucket
#define NBKT 782              // ceil(NN/BSZ)
#define NPB 256               // partition blocks
#define EPB 6250              // edges per partition block (NE/NPB, exact)

typedef unsigned short u16;
typedef unsigned int   u32;
typedef __attribute__((ext_vector_type(8))) __bf16 bf16x8;
typedef __attribute__((ext_vector_type(4))) float  f32x4;

__device__ __forceinline__ float bf2f(u16 u) {
    union { u32 i; float f; } v; v.i = ((u32)u) << 16; return v.f;
}
__device__ __forceinline__ u16 f2bf(float f) {
    union { float f; u32 i; } v; v.f = f;
    u32 u = v.i;
    u += 0x7FFFu + ((u >> 16) & 1);   // round-to-nearest-even
    return (u16)(u >> 16);
}

// ---------------- zero bucket counters ----------------
__global__ __launch_bounds__(256) void k_zero(int* __restrict__ bktcnt) {
    int i = blockIdx.x * 256 + threadIdx.x;
    if (i < NBKT) bktcnt[i] = 0;
}

// ---------------- bucket histogram (LDS-privatized) ----------------
__global__ __launch_bounds__(256) void k_hist(const int* __restrict__ dst,
                                              int* __restrict__ bktcnt) {
    __shared__ int cnt[NBKT];
    int tid = threadIdx.x;
    for (int i = tid; i < NBKT; i += 256) cnt[i] = 0;
    __syncthreads();
    int e0 = blockIdx.x * EPB;
    for (int j = tid; j < EPB; j += 256)
        atomicAdd(&cnt[dst[e0 + j] >> BSH], 1);
    __syncthreads();
    for (int i = tid; i < NBKT; i += 256)
        if (cnt[i]) atomicAdd(&bktcnt[i], cnt[i]);
}

// ---------------- scan 782 bucket counts ----------------
__global__ __launch_bounds__(1024) void k_scan(const int* __restrict__ bktcnt,
                                               int* __restrict__ bktbase,
                                               int* __restrict__ cursor,
                                               int* __restrict__ row_ptr) {
    __shared__ int s[1024];
    int t = threadIdx.x;
    s[t] = (t < NBKT) ? bktcnt[t] : 0;
    __syncthreads();
    #pragma unroll
    for (int off = 1; off < 1024; off <<= 1) {
        int add = (t >= off) ? s[t - off] : 0;
        __syncthreads();
        s[t] += add;
        __syncthreads();
    }
    if (t < NBKT) {
        int b = (t == 0) ? 0 : s[t - 1];
        bktbase[t] = b;
        cursor[t]  = b;
    }
    if (t == 0) { bktbase[NBKT] = NE; row_ptr[NN] = NE; }
}

// ---------------- partition edges into buckets: rec = (w_bits, src<<7|dstLo) ----------------
__global__ __launch_bounds__(256) void k_part(const int* __restrict__ src,
                                              const int* __restrict__ dst,
                                              const float* __restrict__ w,
                                              int* __restrict__ cursor,
                                              uint2* __restrict__ rec) {
    __shared__ int cnt[NBKT];
    __shared__ int base[NBKT];
    int tid = threadIdx.x;
    for (int i = tid; i < NBKT; i += 256) cnt[i] = 0;
    __syncthreads();
    int e0 = blockIdx.x * EPB;
    for (int j = tid; j < EPB; j += 256)
        atomicAdd(&cnt[dst[e0 + j] >> BSH], 1);
    __syncthreads();
    for (int i = tid; i < NBKT; i += 256) {
        int c = cnt[i];
        base[i] = c ? atomicAdd(&cursor[i], c) : 0;  // one global atomic per (block,bucket)
    }
    __syncthreads();
    for (int i = tid; i < NBKT; i += 256) cnt[i] = 0;
    __syncthreads();
    for (int j = tid; j < EPB; j += 256) {
        int e  = e0 + j;
        int d  = dst[e];
        int bk = d >> BSH;
        int slot = base[bk] + atomicAdd(&cnt[bk], 1);   // LDS cursor
        rec[slot] = make_uint2(__float_as_uint(w[e]),
                               ((u32)src[e] << BSH) | (u32)(d & (BSZ - 1)));
    }
}

// ---------------- per-bucket: deg -> dis, counting-sort to per-node CSR ----------------
// rec2[pos] = (w * dis[dst], src) sorted by dst; row_ptr[node] = start
__global__ __launch_bounds__(256) void k_build(const int* __restrict__ bktbase,
                                               const uint2* __restrict__ rec,
                                               uint2* __restrict__ rec2,
                                               float* __restrict__ dis,
                                               int* __restrict__ row_ptr) {
    __shared__ float dw[BSZ];
    __shared__ int   cnt[BSZ];
    __shared__ int   base[BSZ];
    __shared__ int   scn[BSZ];
    __shared__ float disl[BSZ];
    int b = blockIdx.x, tid = threadIdx.x;
    int s = bktbase[b], e = bktbase[b + 1];
    if (tid < BSZ) { dw[tid] = 1.0f; cnt[tid] = 0; }   // self-loop weight
    __syncthreads();
    for (int j = s + tid; j < e; j += 256) {
        uint2 r = rec[j];
        int dl = r.y & (BSZ - 1);
        atomicAdd(&cnt[dl], 1);
        atomicAdd(&dw[dl], __uint_as_float(r.x));
    }
    __syncthreads();
    if (tid < BSZ) scn[tid] = cnt[tid];
    __syncthreads();
    #pragma unroll
    for (int off = 1; off < BSZ; off <<= 1) {          // Hillis-Steele over 128
        int add = (tid < BSZ && tid >= off) ? scn[tid - off] : 0;
        __syncthreads();
        if (tid < BSZ) scn[tid] += add;
        __syncthreads();
    }
    if (tid < BSZ) {
        int node = b * BSZ + tid;
        base[tid] = (tid == 0) ? 0 : scn[tid - 1];
        float d = rsqrtf(dw[tid]);                     // dw >= 1 always
        disl[tid] = d;
        if (node < NN) { dis[node] = d; row_ptr[node] = s + base[tid]; }
        cnt[tid] = 0;                                   // reuse as cursor
    }
    __syncthreads();
    for (int j = s + tid; j < e; j += 256) {
        uint2 r = rec[j];
        int dl = r.y & (BSZ - 1);
        int pos = s + base[dl] + atomicAdd(&cnt[dl], 1);
        rec2[pos] = make_uint2(__float_as_uint(__uint_as_float(r.x) * disl[dl]),
                               r.y >> BSH);
    }
}

// ---------------- pack W1/W2 into MFMA B-fragment order ----------------
// frag layout (16x16x32 bf16): lane l holds B[k=(l>>4)*8+i][col=l&15], i=0..7
// wp1: frag q = kb*4+ct (kb: k-block of 32, ct: 16-col tile) -> [q][lane]
// wp2: frag q = kb (ct=0, N=16)                              -> [q][lane]
__global__ __launch_bounds__(256) void k_wpack(const float* __restrict__ W1,
                                               const float* __restrict__ W2,
                                               bf16x8* __restrict__ wp1,
                                               bf16x8* __restrict__ wp2) {
    int t = threadIdx.x;
    #pragma unroll
    for (int s = 0; s < 4; ++s) {
        int idx = s * 256 + t;          // 0..1023
        int q = idx >> 6, l = idx & 63;
        int kb = q >> 2, ct = q & 3;
        int k0 = kb * 32 + ((l >> 4) * 8);
        int c  = ct * 16 + (l & 15);
        bf16x8 v;
        #pragma unroll
        for (int i = 0; i < 8; ++i) v[i] = (__bf16)W1[(k0 + i) * 64 + c];
        wp1[idx] = v;
    }
    if (t < 128) {
        int q = t >> 6, l = t & 63;
        int k0 = q * 32 + ((l >> 4) * 8);
        int c  = l & 15;
        bf16x8 v;
        #pragma unroll
        for (int i = 0; i < 8; ++i) v[i] = (__bf16)W2[(k0 + i) * 16 + c];
        wp2[t] = v;
    }
}

// ---------------- h1b = bf16(dis * (x @ W1)) via MFMA ----------------
// 4 waves/block, 16 rows/wave; no LDS, no syncthreads.
__global__ __launch_bounds__(256) void k_gemm1(const float* __restrict__ x,
                                               const bf16x8* __restrict__ wp1,
                                               const float* __restrict__ dis,
                                               u16* __restrict__ h1b) {
    int tid  = threadIdx.x;
    int lane = tid & 63;
    int wave = tid >> 6;
    int r0   = blockIdx.x * 64 + wave * 16;

    bf16x8 bfrag[16];
    #pragma unroll
    for (int q = 0; q < 16; ++q) bfrag[q] = wp1[q * 64 + lane];  // coalesced, L2-hot

    int  arow = r0 + (lane & 15);
    bool aok  = arow < NN;
    const float* xrow = x + (size_t)arow * 128 + ((lane >> 4) * 8);

    f32x4 acc0 = {0,0,0,0}, acc1 = {0,0,0,0}, acc2 = {0,0,0,0}, acc3 = {0,0,0,0};
    #pragma unroll
    for (int kb = 0; kb < 4; ++kb) {
        f32x4 xlo = {0,0,0,0}, xhi = {0,0,0,0};
        if (aok) {
            xlo = *(const f32x4*)(xrow + kb * 32);
            xhi = *(const f32x4*)(xrow + kb * 32 + 4);
        }
        bf16x8 a;
        a[0] = (__bf16)xlo[0]; a[1] = (__bf16)xlo[1]; a[2] = (__bf16)xlo[2]; a[3] = (__bf16)xlo[3];
        a[4] = (__bf16)xhi[0]; a[5] = (__bf16)xhi[1]; a[6] = (__bf16)xhi[2]; a[7] = (__bf16)xhi[3];
        acc0 = __builtin_amdgcn_mfma_f32_16x16x32_bf16(a, bfrag[kb * 4 + 0], acc0, 0, 0, 0);
        acc1 = __builtin_amdgcn_mfma_f32_16x16x32_bf16(a, bfrag[kb * 4 + 1], acc1, 0, 0, 0);
        acc2 = __builtin_amdgcn_mfma_f32_16x16x32_bf16(a, bfrag[kb * 4 + 2], acc2, 0, 0, 0);
        acc3 = __builtin_amdgcn_mfma_f32_16x16x32_bf16(a, bfrag[kb * 4 + 3], acc3, 0, 0, 0);
    }

    // D: col = ct*16 + (lane&15), row = r0 + (lane>>4)*4 + reg
    int rbase = r0 + (lane >> 4) * 4;
    int cbase = lane & 15;
    #pragma unroll
    for (int reg = 0; reg < 4; ++reg) {
        int row = rbase + reg;
        if (row < NN) {
            float d = dis[row];
            u16* hp = h1b + (size_t)row * 64 + cbase;
            hp[0]  = f2bf(acc0[reg] * d);
            hp[16] = f2bf(acc1[reg] * d);
            hp[32] = f2bf(acc2[reg] * d);
            hp[48] = f2bf(acc3[reg] * d);
        }
    }
}

// ---------------- layer-1 aggregation: one wave per node, lane = feature ----------------
__global__ __launch_bounds__(256) void k_agg1(const int* __restrict__ row_ptr,
                                              const uint2* __restrict__ rec2,
                                              const u16* __restrict__ h1b,
                                              const float* __restrict__ dis,
                                              const float* __restrict__ b1,
                                              float* __restrict__ xemb) {
    int n = (blockIdx.x * 256 + threadIdx.x) >> 6;
    int f = threadIdx.x & 63;
    float di = dis[n];
    float acc = fmaf(di, bf2f(h1b[(size_t)n * 64 + f]), b1[f]);  // self-loop: dis^2*h1 = dis*h1b
    int j = row_ptr[n], end = row_ptr[n + 1];
    for (; j + 7 < end; j += 8) {   // 8-deep: eight gathers in flight
        uint2 p0 = rec2[j],     p1 = rec2[j + 1], p2 = rec2[j + 2], p3 = rec2[j + 3];
        uint2 p4 = rec2[j + 4], p5 = rec2[j + 5], p6 = rec2[j + 6], p7 = rec2[j + 7];
        float v0 = bf2f(h1b[(size_t)p0.y * 64 + f]);
        float v1 = bf2f(h1b[(size_t)p1.y * 64 + f]);
        float v2 = bf2f(h1b[(size_t)p2.y * 64 + f]);
        float v3 = bf2f(h1b[(size_t)p3.y * 64 + f]);
        float v4 = bf2f(h1b[(size_t)p4.y * 64 + f]);
        float v5 = bf2f(h1b[(size_t)p5.y * 64 + f]);
        float v6 = bf2f(h1b[(size_t)p6.y * 64 + f]);
        float v7 = bf2f(h1b[(size_t)p7.y * 64 + f]);
        acc = fmaf(__uint_as_float(p0.x), v0, acc);
        acc = fmaf(__uint_as_float(p1.x), v1, acc);
        acc = fmaf(__uint_as_float(p2.x), v2, acc);
        acc = fmaf(__uint_as_float(p3.x), v3, acc);
        acc = fmaf(__uint_as_float(p4.x), v4, acc);
        acc = fmaf(__uint_as_float(p5.x), v5, acc);
        acc = fmaf(__uint_as_float(p6.x), v6, acc);
        acc = fmaf(__uint_as_float(p7.x), v7, acc);
    }
    for (; j + 1 < end; j += 2) {
        uint2 p0 = rec2[j], p1 = rec2[j + 1];
        float v0 = bf2f(h1b[(size_t)p0.y * 64 + f]);
        float v1 = bf2f(h1b[(size_t)p1.y * 64 + f]);
        acc = fmaf(__uint_as_float(p0.x), v0, acc);
        acc = fmaf(__uint_as_float(p1.x), v1, acc);
    }
    if (j < end) {
        uint2 p = rec2[j];
        acc = fmaf(__uint_as_float(p.x), bf2f(h1b[(size_t)p.y * 64 + f]), acc);
    }
    xemb[(size_t)n * 64 + f] = acc;
}

// ---------------- h3b = bf16(dis * (relu(xemb) @ W2)) via MFMA ----------------
__global__ __launch_bounds__(256) void k_gemm2(const float* __restrict__ xemb,
                                               const bf16x8* __restrict__ wp2,
                                               const float* __restrict__ dis,
                                               u16* __restrict__ h3b) {
    int tid  = threadIdx.x;
    int lane = tid & 63;
    int wave = tid >> 6;
    int r0   = blockIdx.x * 64 + wave * 16;

    bf16x8 b0 = wp2[lane], b1 = wp2[64 + lane];

    int  arow = r0 + (lane & 15);
    bool aok  = arow < NN;
    const float* xrow = xemb + (size_t)arow * 64 + ((lane >> 4) * 8);

    f32x4 acc = {0,0,0,0};
    #pragma unroll
    for (int kb = 0; kb < 2; ++kb) {
        f32x4 xlo = {0,0,0,0}, xhi = {0,0,0,0};
        if (aok) {
            xlo = *(const f32x4*)(xrow + kb * 32);
            xhi = *(const f32x4*)(xrow + kb * 32 + 4);
        }
        bf16x8 a;
        #pragma unroll
        for (int i = 0; i < 4; ++i) {
            float lo = xlo[i] > 0.f ? xlo[i] : 0.f;   // fused ReLU
            float hi = xhi[i] > 0.f ? xhi[i] : 0.f;
            a[i]     = (__bf16)lo;
            a[i + 4] = (__bf16)hi;
        }
        acc = __builtin_amdgcn_mfma_f32_16x16x32_bf16(a, kb == 0 ? b0 : b1, acc, 0, 0, 0);
    }

    int rbase = r0 + (lane >> 4) * 4;
    int cbase = lane & 15;
    #pragma unroll
    for (int reg = 0; reg < 4; ++reg) {
        int row = rbase + reg;
        if (row < NN)
            h3b[(size_t)row * 16 + cbase] = f2bf(acc[reg] * dis[row]);
    }
}

// ---------------- layer-2 aggregation: wave = node, 16 feats x 4 edge groups ----------------
__global__ __launch_bounds__(256) void k_agg2(const int* __restrict__ row_ptr,
                                              const uint2* __restrict__ rec2,
                                              const u16* __restrict__ h3b,
                                              const float* __restrict__ dis,
                                              const float* __restrict__ b2,
                                              float* __restrict__ out) {
    int n    = (blockIdx.x * 256 + threadIdx.x) >> 6;
    int lane = threadIdx.x & 63;
    int f = lane & 15, g = lane >> 4;
    int start = row_ptr[n], end = row_ptr[n + 1];
    float acc = 0.f;
    int j = start + g;
    for (; j + 4 < end; j += 8) {     // 2 per group in flight
        uint2 p0 = rec2[j], p1 = rec2[j + 4];
        float v0 = bf2f(h3b[(size_t)p0.y * 16 + f]);
        float v1 = bf2f(h3b[(size_t)p1.y * 16 + f]);
        acc = fmaf(__uint_as_float(p0.x), v0, acc);
        acc = fmaf(__uint_as_float(p1.x), v1, acc);
    }
    if (j < end) {
        uint2 p = rec2[j];
        acc = fmaf(__uint_as_float(p.x), bf2f(h3b[(size_t)p.y * 16 + f]), acc);
    }
    acc += __shfl_xor(acc, 16, 64);   // reduce the 4 edge groups
    acc += __shfl_xor(acc, 32, 64);
    if (g == 0) {
        float di = dis[n];
        out[(size_t)n * 16 + f] = fmaf(di, bf2f(h3b[(size_t)n * 16 + f]), b2[f]) + acc;
    }
}

extern "C" void kernel_launch(void* const* d_in, const int* in_sizes, int n_in,
                              void* d_out, int out_size, void* d_ws, size_t ws_size,
                              hipStream_t stream) {
    const float* x  = (const float*)d_in[0];
    const int*   ei = (const int*)d_in[1];
    const float* w  = (const float*)d_in[2];
    const float* W1 = (const float*)d_in[3];
    const float* b1 = (const float*)d_in[4];
    const float* W2 = (const float*)d_in[5];
    const float* b2 = (const float*)d_in[6];
    const int* src = ei;
    const int* dst = ei + NE;

    float* out2 = (float*)d_out;               // [NN,16]  output 0
    float* xemb = (float*)d_out + NN * 16;     // [NN,64]  output 1

    // workspace (~30 MB): h1b ALIASES rec (rec dead after k_build, h1b born at k_gemm1)
    uint2*  rec     = (uint2*)d_ws;                     // NE uint2 = 12.8MB (stage 1)
    u16*    h1b     = (u16*)d_ws;                       // NN*64 u16 = 12.8MB (alias)
    uint2*  rec2    = (uint2*)((char*)d_ws + (size_t)NE * 8);  // NE uint2 = 12.8MB
    u16*    h3b     = (u16*)(rec2 + NE);                // NN*16 u16 = 3.2MB
    bf16x8* wp1     = (bf16x8*)(h3b + (size_t)NN * 16); // 1024 * 16B = 16KB
    bf16x8* wp2     = wp1 + 1024;                       // 128 * 16B = 2KB
    float*  dis     = (float*)(wp2 + 128);              // NN
    int*    row_ptr = (int*)(dis + NN);                 // NN+1
    int*    bktcnt  = row_ptr + NN + 2;                 // NBKT
    int*    bktbase = bktcnt + NBKT;                    // NBKT+1
    int*    cursor  = bktbase + NBKT + 1;               // NBKT

    // --- build (shared by both layers) ---
    k_zero <<<(NBKT + 255) / 256, 256, 0, stream>>>(bktcnt);
    k_hist <<<NPB,  256, 0, stream>>>(dst, bktcnt);
    k_scan <<<1,   1024, 0, stream>>>(bktcnt, bktbase, cursor, row_ptr);
    k_part <<<NPB,  256, 0, stream>>>(src, dst, w, cursor, rec);
    k_build<<<NBKT, 256, 0, stream>>>(bktbase, rec, rec2, dis, row_ptr);
    k_wpack<<<1,    256, 0, stream>>>(W1, W2, wp1, wp2);

    // --- layer 1 ---
    k_gemm1<<<(NN + 63) / 64, 256, 0, stream>>>(x, wp1, dis, h1b);
    k_agg1 <<<NN * 64 / 256, 256, 0, stream>>>(row_ptr, rec2, h1b, dis, b1, xemb);

    // --- layer 2 ---
    k_gemm2<<<(NN + 63) / 64, 256, 0, stream>>>(xemb, wp2, dis, h3b);
    k_agg2 <<<NN * 64 / 256, 256, 0, stream>>>(row_ptr, rec2, h3b, dis, b2, out2);
}

// Round 9
// 186.243 us; speedup vs baseline: 5.2928x; 1.0772x over previous
//
#include <hip/hip_runtime.h>

#define NN 100000
#define NE 1600000
#define BSH 7                 // log2(nodes per bucket)
#define BSZ 128               // nodes per bucket
#define NBKT 782              // ceil(NN/BSZ)
#define CAP 2560              // padded slots per bucket (mean 2048, sd ~45 -> 11 sigma)
#define NPB 256               // partition blocks
#define EPB 6250              // edges per partition block (NE/NPB, exact)

typedef unsigned short u16;
typedef unsigned int   u32;
typedef __attribute__((ext_vector_type(8))) __bf16 bf16x8;
typedef __attribute__((ext_vector_type(4))) float  f32x4;

__device__ __forceinline__ float bf2f(u16 u) {
    union { u32 i; float f; } v; v.i = ((u32)u) << 16; return v.f;
}
__device__ __forceinline__ u16 f2bf(float f) {
    union { float f; u32 i; } v; v.f = f;
    u32 u = v.i;
    u += 0x7FFFu + ((u >> 16) & 1);   // round-to-nearest-even
    return (u16)(u >> 16);
}
__device__ __forceinline__ float bfLO(u32 p) { return __uint_as_float(p << 16); }
__device__ __forceinline__ float bfHI(u32 p) { return __uint_as_float(p & 0xffff0000u); }

// ---------------- pack W1/W2 into MFMA B-frag order; init cursors ----------------
// frag layout (16x16x32 bf16): lane l holds B[k=(l>>4)*8+i][col=l&15], i=0..7
__global__ __launch_bounds__(256) void k_wpack(const float* __restrict__ W1,
                                               const float* __restrict__ W2,
                                               bf16x8* __restrict__ wp1,
                                               bf16x8* __restrict__ wp2,
                                               int* __restrict__ cursor,
                                               int* __restrict__ gctr) {
    int t = threadIdx.x;
    #pragma unroll
    for (int s = 0; s < 4; ++s) {
        int idx = s * 256 + t;          // 0..1023
        int q = idx >> 6, l = idx & 63;
        int kb = q >> 2, ct = q & 3;
        int k0 = kb * 32 + ((l >> 4) * 8);
        int c  = ct * 16 + (l & 15);
        bf16x8 v;
        #pragma unroll
        for (int i = 0; i < 8; ++i) v[i] = (__bf16)W1[(k0 + i) * 64 + c];
        wp1[idx] = v;
    }
    if (t < 128) {
        int q = t >> 6, l = t & 63;
        int k0 = q * 32 + ((l >> 4) * 8);
        int c  = l & 15;
        bf16x8 v;
        #pragma unroll
        for (int i = 0; i < 8; ++i) v[i] = (__bf16)W2[(k0 + i) * 16 + c];
        wp2[t] = v;
    }
    for (int i = t; i < NBKT; i += 256) cursor[i] = i * CAP;   // padded bucket bases
    if (t == 0) *gctr = 0;
}

// ---------------- partition edges into padded buckets: rec = (w_bits, src<<7|dstLo) ----------------
__global__ __launch_bounds__(256) void k_part(const int* __restrict__ src,
                                              const int* __restrict__ dst,
                                              const float* __restrict__ w,
                                              int* __restrict__ cursor,
                                              uint2* __restrict__ rec) {
    __shared__ int cnt[NBKT];
    __shared__ int base[NBKT];
    int tid = threadIdx.x;
    for (int i = tid; i < NBKT; i += 256) cnt[i] = 0;
    __syncthreads();
    int e0 = blockIdx.x * EPB;
    for (int j = tid; j < EPB; j += 256)
        atomicAdd(&cnt[dst[e0 + j] >> BSH], 1);
    __syncthreads();
    for (int i = tid; i < NBKT; i += 256) {
        int c = cnt[i];
        base[i] = c ? atomicAdd(&cursor[i], c) : 0;  // one global atomic per (block,bucket)
    }
    __syncthreads();
    for (int i = tid; i < NBKT; i += 256) cnt[i] = 0;
    __syncthreads();
    for (int j = tid; j < EPB; j += 256) {
        int e  = e0 + j;
        int d  = dst[e];
        int bk = d >> BSH;
        int slot = base[bk] + atomicAdd(&cnt[bk], 1);   // LDS cursor; global padded index
        rec[slot] = make_uint2(__float_as_uint(w[e]),
                               ((u32)src[e] << BSH) | (u32)(d & (BSZ - 1)));
    }
}

// ---------------- per-bucket: deg -> dis, counting-sort to dense per-node CSR ----------------
// rec2[pos] = (w * dis[dst], src) grouped by dst; rowinfo[node] = (beg, end)
__global__ __launch_bounds__(256) void k_build(const int* __restrict__ cursor,
                                               const uint2* __restrict__ rec,
                                               uint2* __restrict__ rec2,
                                               float* __restrict__ dis,
                                               int2* __restrict__ rowinfo,
                                               int* __restrict__ gctr) {
    __shared__ float dw[BSZ];
    __shared__ int   cnt[BSZ];
    __shared__ int   base[BSZ];
    __shared__ int   scn[BSZ];
    __shared__ float disl[BSZ];
    __shared__ int   sh_gbase;
    int b = blockIdx.x, tid = threadIdx.x;
    int s = b * CAP;
    int total = cursor[b] - s;          // edges in this bucket
    if (tid < BSZ) { dw[tid] = 1.0f; cnt[tid] = 0; }   // self-loop weight
    if (tid == 0) sh_gbase = atomicAdd(gctr, total);   // dense reservation
    __syncthreads();
    for (int j = tid; j < total; j += 256) {
        uint2 r = rec[s + j];
        int dl = r.y & (BSZ - 1);
        atomicAdd(&cnt[dl], 1);
        atomicAdd(&dw[dl], __uint_as_float(r.x));
    }
    __syncthreads();
    if (tid < BSZ) scn[tid] = cnt[tid];
    __syncthreads();
    #pragma unroll
    for (int off = 1; off < BSZ; off <<= 1) {          // Hillis-Steele over 128
        int add = (tid < BSZ && tid >= off) ? scn[tid - off] : 0;
        __syncthreads();
        if (tid < BSZ) scn[tid] += add;
        __syncthreads();
    }
    int gbase = sh_gbase;
    if (tid < BSZ) {
        int node = b * BSZ + tid;
        base[tid] = (tid == 0) ? 0 : scn[tid - 1];
        float d = rsqrtf(dw[tid]);                     // dw >= 1 always
        disl[tid] = d;
        if (node < NN) {
            dis[node] = d;
            rowinfo[node] = make_int2(gbase + base[tid], gbase + base[tid] + cnt[tid]);
        }
        cnt[tid] = 0;                                   // reuse as cursor
    }
    __syncthreads();
    for (int j = tid; j < total; j += 256) {
        uint2 r = rec[s + j];
        int dl = r.y & (BSZ - 1);
        int pos = gbase + base[dl] + atomicAdd(&cnt[dl], 1);
        rec2[pos] = make_uint2(__float_as_uint(__uint_as_float(r.x) * disl[dl]),
                               r.y >> BSH);
    }
}

// ---------------- h1b = bf16(dis * (x @ W1)) via MFMA ----------------
__global__ __launch_bounds__(256) void k_gemm1(const float* __restrict__ x,
                                               const bf16x8* __restrict__ wp1,
                                               const float* __restrict__ dis,
                                               u16* __restrict__ h1b) {
    int tid  = threadIdx.x;
    int lane = tid & 63;
    int wave = tid >> 6;
    int r0   = blockIdx.x * 64 + wave * 16;

    bf16x8 bfrag[16];
    #pragma unroll
    for (int q = 0; q < 16; ++q) bfrag[q] = wp1[q * 64 + lane];  // coalesced, L2-hot

    int  arow = r0 + (lane & 15);
    bool aok  = arow < NN;
    const float* xrow = x + (size_t)arow * 128 + ((lane >> 4) * 8);

    f32x4 acc0 = {0,0,0,0}, acc1 = {0,0,0,0}, acc2 = {0,0,0,0}, acc3 = {0,0,0,0};
    #pragma unroll
    for (int kb = 0; kb < 4; ++kb) {
        f32x4 xlo = {0,0,0,0}, xhi = {0,0,0,0};
        if (aok) {
            xlo = *(const f32x4*)(xrow + kb * 32);
            xhi = *(const f32x4*)(xrow + kb * 32 + 4);
        }
        bf16x8 a;
        a[0] = (__bf16)xlo[0]; a[1] = (__bf16)xlo[1]; a[2] = (__bf16)xlo[2]; a[3] = (__bf16)xlo[3];
        a[4] = (__bf16)xhi[0]; a[5] = (__bf16)xhi[1]; a[6] = (__bf16)xhi[2]; a[7] = (__bf16)xhi[3];
        acc0 = __builtin_amdgcn_mfma_f32_16x16x32_bf16(a, bfrag[kb * 4 + 0], acc0, 0, 0, 0);
        acc1 = __builtin_amdgcn_mfma_f32_16x16x32_bf16(a, bfrag[kb * 4 + 1], acc1, 0, 0, 0);
        acc2 = __builtin_amdgcn_mfma_f32_16x16x32_bf16(a, bfrag[kb * 4 + 2], acc2, 0, 0, 0);
        acc3 = __builtin_amdgcn_mfma_f32_16x16x32_bf16(a, bfrag[kb * 4 + 3], acc3, 0, 0, 0);
    }

    int rbase = r0 + (lane >> 4) * 4;
    int cbase = lane & 15;
    #pragma unroll
    for (int reg = 0; reg < 4; ++reg) {
        int row = rbase + reg;
        if (row < NN) {
            float d = dis[row];
            u16* hp = h1b + (size_t)row * 64 + cbase;
            hp[0]  = f2bf(acc0[reg] * d);
            hp[16] = f2bf(acc1[reg] * d);
            hp[32] = f2bf(acc2[reg] * d);
            hp[48] = f2bf(acc3[reg] * d);
        }
    }
}

// ---------------- layer-1 aggregation: wave = node, 16 lanes x 4 features per edge ----------------
// 4 edges per iteration step, x4 unroll = 16 edges in flight.
__global__ __launch_bounds__(256) void k_agg1(const int2* __restrict__ rowinfo,
                                              const uint2* __restrict__ rec2,
                                              const u16* __restrict__ h1b,
                                              const float* __restrict__ dis,
                                              const float* __restrict__ b1,
                                              float* __restrict__ xemb) {
    int n    = (blockIdx.x * 256 + threadIdx.x) >> 6;
    int lane = threadIdx.x & 63;
    int g    = lane >> 4;         // edge slot 0..3
    int f4   = (lane & 15) * 4;   // feature window
    int2 ri  = rowinfo[n];
    int beg = ri.x, end = ri.y;

    float a0 = 0.f, a1 = 0.f, a2 = 0.f, a3 = 0.f;
    for (int j = beg; j < end; j += 16) {
        #pragma unroll
        for (int s = 0; s < 4; ++s) {
            int e = j + s * 4 + g;
            if (e < end) {
                uint2 p  = rec2[e];
                uint2 hv = *(const uint2*)(h1b + (size_t)p.y * 64 + f4);  // 4 bf16
                float nrm = __uint_as_float(p.x);
                a0 = fmaf(nrm, bfLO(hv.x), a0);
                a1 = fmaf(nrm, bfHI(hv.x), a1);
                a2 = fmaf(nrm, bfLO(hv.y), a2);
                a3 = fmaf(nrm, bfHI(hv.y), a3);
            }
        }
    }
    a0 += __shfl_xor(a0, 16, 64); a0 += __shfl_xor(a0, 32, 64);
    a1 += __shfl_xor(a1, 16, 64); a1 += __shfl_xor(a1, 32, 64);
    a2 += __shfl_xor(a2, 16, 64); a2 += __shfl_xor(a2, 32, 64);
    a3 += __shfl_xor(a3, 16, 64); a3 += __shfl_xor(a3, 32, 64);
    if (g == 0) {
        float di = dis[n];
        uint2 hv = *(const uint2*)(h1b + (size_t)n * 64 + f4);   // self-loop
        float4 bb = *(const float4*)&b1[f4];
        float4 r;
        r.x = fmaf(di, bfLO(hv.x), bb.x) + a0;
        r.y = fmaf(di, bfHI(hv.x), bb.y) + a1;
        r.z = fmaf(di, bfLO(hv.y), bb.z) + a2;
        r.w = fmaf(di, bfHI(hv.y), bb.w) + a3;
        *(float4*)&xemb[(size_t)n * 64 + f4] = r;
    }
}

// ---------------- h3b = bf16(dis * (relu(xemb) @ W2)) via MFMA ----------------
__global__ __launch_bounds__(256) void k_gemm2(const float* __restrict__ xemb,
                                               const bf16x8* __restrict__ wp2,
                                               const float* __restrict__ dis,
                                               u16* __restrict__ h3b) {
    int tid  = threadIdx.x;
    int lane = tid & 63;
    int wave = tid >> 6;
    int r0   = blockIdx.x * 64 + wave * 16;

    bf16x8 b0 = wp2[lane], b1 = wp2[64 + lane];

    int  arow = r0 + (lane & 15);
    bool aok  = arow < NN;
    const float* xrow = xemb + (size_t)arow * 64 + ((lane >> 4) * 8);

    f32x4 acc = {0,0,0,0};
    #pragma unroll
    for (int kb = 0; kb < 2; ++kb) {
        f32x4 xlo = {0,0,0,0}, xhi = {0,0,0,0};
        if (aok) {
            xlo = *(const f32x4*)(xrow + kb * 32);
            xhi = *(const f32x4*)(xrow + kb * 32 + 4);
        }
        bf16x8 a;
        #pragma unroll
        for (int i = 0; i < 4; ++i) {
            float lo = xlo[i] > 0.f ? xlo[i] : 0.f;   // fused ReLU
            float hi = xhi[i] > 0.f ? xhi[i] : 0.f;
            a[i]     = (__bf16)lo;
            a[i + 4] = (__bf16)hi;
        }
        acc = __builtin_amdgcn_mfma_f32_16x16x32_bf16(a, kb == 0 ? b0 : b1, acc, 0, 0, 0);
    }

    int rbase = r0 + (lane >> 4) * 4;
    int cbase = lane & 15;
    #pragma unroll
    for (int reg = 0; reg < 4; ++reg) {
        int row = rbase + reg;
        if (row < NN)
            h3b[(size_t)row * 16 + cbase] = f2bf(acc[reg] * dis[row]);
    }
}

// ---------------- layer-2 aggregation: wave = node, 4 lanes x 4 features per edge ----------------
// 16 edges per step, x2 unroll = 32 edges in flight.
__global__ __launch_bounds__(256) void k_agg2(const int2* __restrict__ rowinfo,
                                              const uint2* __restrict__ rec2,
                                              const u16* __restrict__ h3b,
                                              const float* __restrict__ dis,
                                              const float* __restrict__ b2,
                                              float* __restrict__ out) {
    int n    = (blockIdx.x * 256 + threadIdx.x) >> 6;
    int lane = threadIdx.x & 63;
    int el   = lane >> 2;        // edge slot 0..15
    int f4   = (lane & 3) * 4;   // feature window
    int2 ri  = rowinfo[n];
    int beg = ri.x, end = ri.y;

    float a0 = 0.f, a1 = 0.f, a2 = 0.f, a3 = 0.f;
    for (int j = beg; j < end; j += 32) {
        #pragma unroll
        for (int s = 0; s < 2; ++s) {
            int e = j + s * 16 + el;
            if (e < end) {
                uint2 p  = rec2[e];
                uint2 hv = *(const uint2*)(h3b + (size_t)p.y * 16 + f4);
                float nrm = __uint_as_float(p.x);
                a0 = fmaf(nrm, bfLO(hv.x), a0);
                a1 = fmaf(nrm, bfHI(hv.x), a1);
                a2 = fmaf(nrm, bfLO(hv.y), a2);
                a3 = fmaf(nrm, bfHI(hv.y), a3);
            }
        }
    }
    #pragma unroll
    for (int m = 4; m <= 32; m <<= 1) {
        a0 += __shfl_xor(a0, m, 64);
        a1 += __shfl_xor(a1, m, 64);
        a2 += __shfl_xor(a2, m, 64);
        a3 += __shfl_xor(a3, m, 64);
    }
    if (lane < 4) {
        float di = dis[n];
        uint2 hv = *(const uint2*)(h3b + (size_t)n * 16 + f4);   // self-loop
        float4 bb = *(const float4*)&b2[f4];
        float4 r;
        r.x = fmaf(di, bfLO(hv.x), bb.x) + a0;
        r.y = fmaf(di, bfHI(hv.x), bb.y) + a1;
        r.z = fmaf(di, bfLO(hv.y), bb.z) + a2;
        r.w = fmaf(di, bfHI(hv.y), bb.w) + a3;
        *(float4*)&out[(size_t)n * 16 + f4] = r;
    }
}

extern "C" void kernel_launch(void* const* d_in, const int* in_sizes, int n_in,
                              void* d_out, int out_size, void* d_ws, size_t ws_size,
                              hipStream_t stream) {
    const float* x  = (const float*)d_in[0];
    const int*   ei = (const int*)d_in[1];
    const float* w  = (const float*)d_in[2];
    const float* W1 = (const float*)d_in[3];
    const float* b1 = (const float*)d_in[4];
    const float* W2 = (const float*)d_in[5];
    const float* b2 = (const float*)d_in[6];
    const int* src = ei;
    const int* dst = ei + NE;

    float* out2 = (float*)d_out;               // [NN,16]  output 0
    float* xemb = (float*)d_out + NN * 16;     // [NN,64]  output 1

    // workspace (~33 MB): h1b ALIASES rec_pad (rec dead after k_build)
    uint2*  rec_pad = (uint2*)d_ws;                      // NBKT*CAP uint2 = 16.0MB
    u16*    h1b     = (u16*)d_ws;                        // NN*64 u16 = 12.8MB (alias)
    uint2*  rec2    = rec_pad + (size_t)NBKT * CAP;      // NE uint2 = 12.8MB
    u16*    h3b     = (u16*)(rec2 + NE);                 // NN*16 u16 = 3.2MB
    bf16x8* wp1     = (bf16x8*)(h3b + (size_t)NN * 16);  // 16KB
    bf16x8* wp2     = wp1 + 1024;                        // 2KB
    float*  dis     = (float*)(wp2 + 128);               // NN
    int2*   rowinfo = (int2*)(dis + NN);                 // NN int2
    int*    cursor  = (int*)(rowinfo + NN);              // NBKT
    int*    gctr    = cursor + NBKT;                     // 1

    // --- build (shared by both layers) ---
    k_wpack<<<1,    256, 0, stream>>>(W1, W2, wp1, wp2, cursor, gctr);
    k_part <<<NPB,  256, 0, stream>>>(src, dst, w, cursor, rec_pad);
    k_build<<<NBKT, 256, 0, stream>>>(cursor, rec_pad, rec2, dis, rowinfo, gctr);

    // --- layer 1 ---
    k_gemm1<<<(NN + 63) / 64, 256, 0, stream>>>(x, wp1, dis, h1b);
    k_agg1 <<<NN / 4, 256, 0, stream>>>(rowinfo, rec2, h1b, dis, b1, xemb);

    // --- layer 2 ---
    k_gemm2<<<(NN + 63) / 64, 256, 0, stream>>>(xemb, wp2, dis, h3b);
    k_agg2 <<<NN / 4, 256, 0, stream>>>(rowinfo, rec2, h3b, dis, b2, out2);
}

// Round 10
// 179.275 us; speedup vs baseline: 5.4986x; 1.0389x over previous
//
#include <hip/hip_runtime.h>

#define NN 100000
#define NE 1600000
#define BSH 7                 // log2(nodes per bucket)
#define BSZ 128               // nodes per bucket
#define NBKT 782              // ceil(NN/BSZ)
#define CAP 2560              // padded slots per bucket (mean 2048, sd ~45 -> 11 sigma)
#define NPB 256               // partition blocks
#define EPB 6250              // edges per partition block (NE/NPB, exact)

typedef unsigned short u16;
typedef unsigned int   u32;
typedef unsigned long long u64;
typedef __attribute__((ext_vector_type(8))) __bf16 bf16x8;
typedef __attribute__((ext_vector_type(4))) float  f32x4;
typedef __attribute__((ext_vector_type(4))) u32    u32x4;

__device__ __forceinline__ float bf2f(u16 u) {
    union { u32 i; float f; } v; v.i = ((u32)u) << 16; return v.f;
}
__device__ __forceinline__ u16 f2bf(float f) {
    union { float f; u32 i; } v; v.f = f;
    u32 u = v.i;
    u += 0x7FFFu + ((u >> 16) & 1);   // round-to-nearest-even
    return (u16)(u >> 16);
}
__device__ __forceinline__ float bfLO(u32 p) { return __uint_as_float(p << 16); }
__device__ __forceinline__ float bfHI(u32 p) { return __uint_as_float(p & 0xffff0000u); }

// ---------------- pack W1/W2 into MFMA B-frag order; init cursors ----------------
__global__ __launch_bounds__(256) void k_wpack(const float* __restrict__ W1,
                                               const float* __restrict__ W2,
                                               bf16x8* __restrict__ wp1,
                                               bf16x8* __restrict__ wp2,
                                               int* __restrict__ cursor,
                                               int* __restrict__ gctr) {
    int t = threadIdx.x;
    #pragma unroll
    for (int s = 0; s < 4; ++s) {
        int idx = s * 256 + t;          // 0..1023
        int q = idx >> 6, l = idx & 63;
        int kb = q >> 2, ct = q & 3;
        int k0 = kb * 32 + ((l >> 4) * 8);
        int c  = ct * 16 + (l & 15);
        bf16x8 v;
        #pragma unroll
        for (int i = 0; i < 8; ++i) v[i] = (__bf16)W1[(k0 + i) * 64 + c];
        wp1[idx] = v;
    }
    if (t < 128) {
        int q = t >> 6, l = t & 63;
        int k0 = q * 32 + ((l >> 4) * 8);
        int c  = l & 15;
        bf16x8 v;
        #pragma unroll
        for (int i = 0; i < 8; ++i) v[i] = (__bf16)W2[(k0 + i) * 16 + c];
        wp2[t] = v;
    }
    for (int i = t; i < NBKT; i += 256) cursor[i] = i * CAP;   // padded bucket bases
    if (t == 0) *gctr = 0;
}

// ---------------- partition edges into padded buckets ----------------
__global__ __launch_bounds__(256) void k_part(const int* __restrict__ src,
                                              const int* __restrict__ dst,
                                              const float* __restrict__ w,
                                              int* __restrict__ cursor,
                                              uint2* __restrict__ rec) {
    __shared__ int cnt[NBKT];
    __shared__ int base[NBKT];
    int tid = threadIdx.x;
    for (int i = tid; i < NBKT; i += 256) cnt[i] = 0;
    __syncthreads();
    int e0 = blockIdx.x * EPB;
    for (int j = tid; j < EPB; j += 256)
        atomicAdd(&cnt[dst[e0 + j] >> BSH], 1);
    __syncthreads();
    for (int i = tid; i < NBKT; i += 256) {
        int c = cnt[i];
        base[i] = c ? atomicAdd(&cursor[i], c) : 0;  // one global atomic per (block,bucket)
    }
    __syncthreads();
    for (int i = tid; i < NBKT; i += 256) cnt[i] = 0;
    __syncthreads();
    for (int j = tid; j < EPB; j += 256) {
        int e  = e0 + j;
        int d  = dst[e];
        int bk = d >> BSH;
        int slot = base[bk] + atomicAdd(&cnt[bk], 1);   // LDS cursor; global padded index
        rec[slot] = make_uint2(__float_as_uint(w[e]),
                               ((u32)src[e] << BSH) | (u32)(d & (BSZ - 1)));
    }
}

// ---------------- per-bucket: deg -> dis, counting-sort to dense per-node CSR ----------------
__global__ __launch_bounds__(256) void k_build(const int* __restrict__ cursor,
                                               const uint2* __restrict__ rec,
                                               uint2* __restrict__ rec2,
                                               float* __restrict__ dis,
                                               int2* __restrict__ rowinfo,
                                               int* __restrict__ gctr) {
    __shared__ float dw[BSZ];
    __shared__ int   cnt[BSZ];
    __shared__ int   base[BSZ];
    __shared__ int   scn[BSZ];
    __shared__ float disl[BSZ];
    __shared__ int   sh_gbase;
    int b = blockIdx.x, tid = threadIdx.x;
    int s = b * CAP;
    int total = cursor[b] - s;          // edges in this bucket
    if (tid < BSZ) { dw[tid] = 1.0f; cnt[tid] = 0; }   // self-loop weight
    if (tid == 0) sh_gbase = atomicAdd(gctr, total);   // dense reservation
    __syncthreads();
    for (int j = tid; j < total; j += 256) {
        uint2 r = rec[s + j];
        int dl = r.y & (BSZ - 1);
        atomicAdd(&cnt[dl], 1);
        atomicAdd(&dw[dl], __uint_as_float(r.x));
    }
    __syncthreads();
    if (tid < BSZ) scn[tid] = cnt[tid];
    __syncthreads();
    #pragma unroll
    for (int off = 1; off < BSZ; off <<= 1) {          // Hillis-Steele over 128
        int add = (tid < BSZ && tid >= off) ? scn[tid - off] : 0;
        __syncthreads();
        if (tid < BSZ) scn[tid] += add;
        __syncthreads();
    }
    int gbase = sh_gbase;
    if (tid < BSZ) {
        int node = b * BSZ + tid;
        base[tid] = (tid == 0) ? 0 : scn[tid - 1];
        float d = rsqrtf(dw[tid]);                     // dw >= 1 always
        disl[tid] = d;
        if (node < NN) {
            dis[node] = d;
            rowinfo[node] = make_int2(gbase + base[tid], gbase + base[tid] + cnt[tid]);
        }
        cnt[tid] = 0;                                   // reuse as cursor
    }
    __syncthreads();
    for (int j = tid; j < total; j += 256) {
        uint2 r = rec[s + j];
        int dl = r.y & (BSZ - 1);
        int pos = gbase + base[dl] + atomicAdd(&cnt[dl], 1);
        rec2[pos] = make_uint2(__float_as_uint(__uint_as_float(r.x) * disl[dl]),
                               r.y >> BSH);
    }
}

// ---------------- h1b = bf16(dis * (x @ W1)) via MFMA ----------------
__global__ __launch_bounds__(256) void k_gemm1(const float* __restrict__ x,
                                               const bf16x8* __restrict__ wp1,
                                               const float* __restrict__ dis,
                                               u16* __restrict__ h1b) {
    int tid  = threadIdx.x;
    int lane = tid & 63;
    int wave = tid >> 6;
    int r0   = blockIdx.x * 64 + wave * 16;

    bf16x8 bfrag[16];
    #pragma unroll
    for (int q = 0; q < 16; ++q) bfrag[q] = wp1[q * 64 + lane];  // coalesced, L2-hot

    int  arow = r0 + (lane & 15);
    bool aok  = arow < NN;
    const float* xrow = x + (size_t)arow * 128 + ((lane >> 4) * 8);

    f32x4 acc0 = {0,0,0,0}, acc1 = {0,0,0,0}, acc2 = {0,0,0,0}, acc3 = {0,0,0,0};
    #pragma unroll
    for (int kb = 0; kb < 4; ++kb) {
        f32x4 xlo = {0,0,0,0}, xhi = {0,0,0,0};
        if (aok) {
            xlo = *(const f32x4*)(xrow + kb * 32);
            xhi = *(const f32x4*)(xrow + kb * 32 + 4);
        }
        bf16x8 a;
        a[0] = (__bf16)xlo[0]; a[1] = (__bf16)xlo[1]; a[2] = (__bf16)xlo[2]; a[3] = (__bf16)xlo[3];
        a[4] = (__bf16)xhi[0]; a[5] = (__bf16)xhi[1]; a[6] = (__bf16)xhi[2]; a[7] = (__bf16)xhi[3];
        acc0 = __builtin_amdgcn_mfma_f32_16x16x32_bf16(a, bfrag[kb * 4 + 0], acc0, 0, 0, 0);
        acc1 = __builtin_amdgcn_mfma_f32_16x16x32_bf16(a, bfrag[kb * 4 + 1], acc1, 0, 0, 0);
        acc2 = __builtin_amdgcn_mfma_f32_16x16x32_bf16(a, bfrag[kb * 4 + 2], acc2, 0, 0, 0);
        acc3 = __builtin_amdgcn_mfma_f32_16x16x32_bf16(a, bfrag[kb * 4 + 3], acc3, 0, 0, 0);
    }

    int rbase = r0 + (lane >> 4) * 4;
    int cbase = lane & 15;
    #pragma unroll
    for (int reg = 0; reg < 4; ++reg) {
        int row = rbase + reg;
        if (row < NN) {
            float d = dis[row];
            u16* hp = h1b + (size_t)row * 64 + cbase;
            hp[0]  = f2bf(acc0[reg] * d);
            hp[16] = f2bf(acc1[reg] * d);
            hp[32] = f2bf(acc2[reg] * d);
            hp[48] = f2bf(acc3[reg] * d);
        }
    }
}

// ---------------- layer-1 aggregation: wave = node, 8 lanes x 8 features per edge ----------------
// 8 edges per gather instruction; rec2 prefetched one full iteration ahead (2 slots);
// nontemporal on rec2 stream and xemb store to protect L2 for h1b gathers.
#define ACC8(hv, nrm) { \
    a0 = fmaf(nrm, bfLO(hv.x), a0); a1 = fmaf(nrm, bfHI(hv.x), a1); \
    a2 = fmaf(nrm, bfLO(hv.y), a2); a3 = fmaf(nrm, bfHI(hv.y), a3); \
    a4 = fmaf(nrm, bfLO(hv.z), a4); a5 = fmaf(nrm, bfHI(hv.z), a5); \
    a6 = fmaf(nrm, bfLO(hv.w), a6); a7 = fmaf(nrm, bfHI(hv.w), a7); }

__device__ __forceinline__ u64 nt_load_u64(const uint2* p) {
    return __builtin_nontemporal_load((const u64*)p);
}

__global__ __launch_bounds__(1024) void k_agg1(const int2* __restrict__ rowinfo,
                                               const uint2* __restrict__ rec2,
                                               const u16* __restrict__ h1b,
                                               const float* __restrict__ dis,
                                               const float* __restrict__ b1,
                                               float* __restrict__ xemb) {
    int n    = blockIdx.x * 16 + (threadIdx.x >> 6);
    int lane = threadIdx.x & 63;
    int el   = lane >> 3;        // edge slot 0..7
    int f8   = (lane & 7) * 8;   // feature window (8 bf16 = 16B)
    int2 ri  = rowinfo[n];
    int beg = ri.x, end = ri.y;

    float a0=0,a1=0,a2=0,a3=0,a4=0,a5=0,a6=0,a7=0;

    u64 p0 = 0, p1 = 0;
    if (beg + el < end)     p0 = nt_load_u64(&rec2[beg + el]);
    if (beg + 8 + el < end) p1 = nt_load_u64(&rec2[beg + 8 + el]);

    for (int j = beg; j < end; j += 16) {
        u64 q0 = 0, q1 = 0;
        if (j + 16 + el < end) q0 = nt_load_u64(&rec2[j + 16 + el]);
        if (j + 24 + el < end) q1 = nt_load_u64(&rec2[j + 24 + el]);
        if (j + el < end) {
            u32 srcn = (u32)(p0 >> 32);
            float nrm = __uint_as_float((u32)p0);
            uint4 hv = *(const uint4*)(h1b + (size_t)srcn * 64 + f8);
            ACC8(hv, nrm);
        }
        if (j + 8 + el < end) {
            u32 srcn = (u32)(p1 >> 32);
            float nrm = __uint_as_float((u32)p1);
            uint4 hv = *(const uint4*)(h1b + (size_t)srcn * 64 + f8);
            ACC8(hv, nrm);
        }
        p0 = q0; p1 = q1;
    }

    #pragma unroll
    for (int m = 8; m <= 32; m <<= 1) {
        a0 += __shfl_xor(a0, m, 64); a1 += __shfl_xor(a1, m, 64);
        a2 += __shfl_xor(a2, m, 64); a3 += __shfl_xor(a3, m, 64);
        a4 += __shfl_xor(a4, m, 64); a5 += __shfl_xor(a5, m, 64);
        a6 += __shfl_xor(a6, m, 64); a7 += __shfl_xor(a7, m, 64);
    }
    if (el == 0) {   // lanes 0..7, each owns 8 features
        float di = dis[n];
        uint4 hv = *(const uint4*)(h1b + (size_t)n * 64 + f8);   // self-loop
        f32x4 lo, hi;
        lo[0] = fmaf(di, bfLO(hv.x), b1[f8 + 0]) + a0;
        lo[1] = fmaf(di, bfHI(hv.x), b1[f8 + 1]) + a1;
        lo[2] = fmaf(di, bfLO(hv.y), b1[f8 + 2]) + a2;
        lo[3] = fmaf(di, bfHI(hv.y), b1[f8 + 3]) + a3;
        hi[0] = fmaf(di, bfLO(hv.z), b1[f8 + 4]) + a4;
        hi[1] = fmaf(di, bfHI(hv.z), b1[f8 + 5]) + a5;
        hi[2] = fmaf(di, bfLO(hv.w), b1[f8 + 6]) + a6;
        hi[3] = fmaf(di, bfHI(hv.w), b1[f8 + 7]) + a7;
        f32x4* dst0 = (f32x4*)&xemb[(size_t)n * 64 + f8];
        __builtin_nontemporal_store(lo, dst0);
        __builtin_nontemporal_store(hi, dst0 + 1);
    }
}

// ---------------- h3b = bf16(dis * (relu(xemb) @ W2)) via MFMA ----------------
__global__ __launch_bounds__(256) void k_gemm2(const float* __restrict__ xemb,
                                               const bf16x8* __restrict__ wp2,
                                               const float* __restrict__ dis,
                                               u16* __restrict__ h3b) {
    int tid  = threadIdx.x;
    int lane = tid & 63;
    int wave = tid >> 6;
    int r0   = blockIdx.x * 64 + wave * 16;

    bf16x8 b0 = wp2[lane], b1 = wp2[64 + lane];

    int  arow = r0 + (lane & 15);
    bool aok  = arow < NN;
    const float* xrow = xemb + (size_t)arow * 64 + ((lane >> 4) * 8);

    f32x4 acc = {0,0,0,0};
    #pragma unroll
    for (int kb = 0; kb < 2; ++kb) {
        f32x4 xlo = {0,0,0,0}, xhi = {0,0,0,0};
        if (aok) {
            xlo = *(const f32x4*)(xrow + kb * 32);
            xhi = *(const f32x4*)(xrow + kb * 32 + 4);
        }
        bf16x8 a;
        #pragma unroll
        for (int i = 0; i < 4; ++i) {
            float lo = xlo[i] > 0.f ? xlo[i] : 0.f;   // fused ReLU
            float hi = xhi[i] > 0.f ? xhi[i] : 0.f;
            a[i]     = (__bf16)lo;
            a[i + 4] = (__bf16)hi;
        }
        acc = __builtin_amdgcn_mfma_f32_16x16x32_bf16(a, kb == 0 ? b0 : b1, acc, 0, 0, 0);
    }

    int rbase = r0 + (lane >> 4) * 4;
    int cbase = lane & 15;
    #pragma unroll
    for (int reg = 0; reg < 4; ++reg) {
        int row = rbase + reg;
        if (row < NN)
            h3b[(size_t)row * 16 + cbase] = f2bf(acc[reg] * dis[row]);
    }
}

// ---------------- layer-2 aggregation: wave = node, 4 lanes x 4 features per edge ----------------
// 16 edges per gather instruction; rec2 prefetched one iteration ahead (2 slots).
__global__ __launch_bounds__(1024) void k_agg2(const int2* __restrict__ rowinfo,
                                               const uint2* __restrict__ rec2,
                                               const u16* __restrict__ h3b,
                                               const float* __restrict__ dis,
                                               const float* __restrict__ b2,
                                               float* __restrict__ out) {
    int n    = blockIdx.x * 16 + (threadIdx.x >> 6);
    int lane = threadIdx.x & 63;
    int el   = lane >> 2;        // edge slot 0..15
    int f4   = (lane & 3) * 4;   // feature window (4 bf16 = 8B)
    int2 ri  = rowinfo[n];
    int beg = ri.x, end = ri.y;

    float a0=0,a1=0,a2=0,a3=0;

    u64 p0 = 0, p1 = 0;
    if (beg + el < end)      p0 = nt_load_u64(&rec2[beg + el]);
    if (beg + 16 + el < end) p1 = nt_load_u64(&rec2[beg + 16 + el]);

    for (int j = beg; j < end; j += 32) {
        u64 q0 = 0, q1 = 0;
        if (j + 32 + el < end) q0 = nt_load_u64(&rec2[j + 32 + el]);
        if (j + 48 + el < end) q1 = nt_load_u64(&rec2[j + 48 + el]);
        if (j + el < end) {
            u32 srcn = (u32)(p0 >> 32);
            float nrm = __uint_as_float((u32)p0);
            uint2 hv = *(const uint2*)(h3b + (size_t)srcn * 16 + f4);
            a0 = fmaf(nrm, bfLO(hv.x), a0); a1 = fmaf(nrm, bfHI(hv.x), a1);
            a2 = fmaf(nrm, bfLO(hv.y), a2); a3 = fmaf(nrm, bfHI(hv.y), a3);
        }
        if (j + 16 + el < end) {
            u32 srcn = (u32)(p1 >> 32);
            float nrm = __uint_as_float((u32)p1);
            uint2 hv = *(const uint2*)(h3b + (size_t)srcn * 16 + f4);
            a0 = fmaf(nrm, bfLO(hv.x), a0); a1 = fmaf(nrm, bfHI(hv.x), a1);
            a2 = fmaf(nrm, bfLO(hv.y), a2); a3 = fmaf(nrm, bfHI(hv.y), a3);
        }
        p0 = q0; p1 = q1;
    }

    #pragma unroll
    for (int m = 4; m <= 32; m <<= 1) {
        a0 += __shfl_xor(a0, m, 64);
        a1 += __shfl_xor(a1, m, 64);
        a2 += __shfl_xor(a2, m, 64);
        a3 += __shfl_xor(a3, m, 64);
    }
    if (lane < 4) {
        float di = dis[n];
        uint2 hv = *(const uint2*)(h3b + (size_t)n * 16 + f4);   // self-loop
        float4 bb = *(const float4*)&b2[f4];
        float4 r;
        r.x = fmaf(di, bfLO(hv.x), bb.x) + a0;
        r.y = fmaf(di, bfHI(hv.x), bb.y) + a1;
        r.z = fmaf(di, bfLO(hv.y), bb.z) + a2;
        r.w = fmaf(di, bfHI(hv.y), bb.w) + a3;
        *(float4*)&out[(size_t)n * 16 + f4] = r;
    }
}

extern "C" void kernel_launch(void* const* d_in, const int* in_sizes, int n_in,
                              void* d_out, int out_size, void* d_ws, size_t ws_size,
                              hipStream_t stream) {
    const float* x  = (const float*)d_in[0];
    const int*   ei = (const int*)d_in[1];
    const float* w  = (const float*)d_in[2];
    const float* W1 = (const float*)d_in[3];
    const float* b1 = (const float*)d_in[4];
    const float* W2 = (const float*)d_in[5];
    const float* b2 = (const float*)d_in[6];
    const int* src = ei;
    const int* dst = ei + NE;

    float* out2 = (float*)d_out;               // [NN,16]  output 0
    float* xemb = (float*)d_out + NN * 16;     // [NN,64]  output 1

    // workspace (~33 MB): h1b ALIASES rec_pad (rec dead after k_build)
    uint2*  rec_pad = (uint2*)d_ws;                      // NBKT*CAP uint2 = 16.0MB
    u16*    h1b     = (u16*)d_ws;                        // NN*64 u16 = 12.8MB (alias)
    uint2*  rec2    = rec_pad + (size_t)NBKT * CAP;      // NE uint2 = 12.8MB
    u16*    h3b     = (u16*)(rec2 + NE);                 // NN*16 u16 = 3.2MB
    bf16x8* wp1     = (bf16x8*)(h3b + (size_t)NN * 16);  // 16KB
    bf16x8* wp2     = wp1 + 1024;                        // 2KB
    float*  dis     = (float*)(wp2 + 128);               // NN
    int2*   rowinfo = (int2*)(dis + NN);                 // NN int2
    int*    cursor  = (int*)(rowinfo + NN);              // NBKT
    int*    gctr    = cursor + NBKT;                     // 1

    // --- build (shared by both layers) ---
    k_wpack<<<1,    256, 0, stream>>>(W1, W2, wp1, wp2, cursor, gctr);
    k_part <<<NPB,  256, 0, stream>>>(src, dst, w, cursor, rec_pad);
    k_build<<<NBKT, 256, 0, stream>>>(cursor, rec_pad, rec2, dis, rowinfo, gctr);

    // --- layer 1 ---
    k_gemm1<<<(NN + 63) / 64, 256, 0, stream>>>(x, wp1, dis, h1b);
    k_agg1 <<<NN / 16, 1024, 0, stream>>>(rowinfo, rec2, h1b, dis, b1, xemb);

    // --- layer 2 ---
    k_gemm2<<<(NN + 63) / 64, 256, 0, stream>>>(xemb, wp2, dis, h3b);
    k_agg2 <<<NN / 16, 1024, 0, stream>>>(rowinfo, rec2, h3b, dis, b2, out2);
}